// Round 6
// baseline (369.934 us; speedup 1.0000x reference)
//
#include <hip/hip_runtime.h>

#define B_ 32
#define S_ 512
#define E_ 1024
#define P_ 256
#define HH 8
// rows = B*S = 16384

typedef __attribute__((ext_vector_type(8))) short bf16x8;
typedef __attribute__((ext_vector_type(8))) unsigned short us8;
typedef __attribute__((ext_vector_type(4))) unsigned short us4;
typedef __attribute__((ext_vector_type(16))) float f32x16;

static __device__ __forceinline__ unsigned short f2bf(float f) {
  union { float f; unsigned int u; } v;
  v.f = f;
  unsigned int r = (v.u + 0x7FFFu + ((v.u >> 16) & 1u)) >> 16;
  return (unsigned short)r;
}
static __device__ __forceinline__ float bf2f(unsigned short u) {
  union { unsigned int u; float f; } v;
  v.u = ((unsigned int)u) << 16;
  return v.f;
}

// ---------------- stage 0a: conv_w (O,I,K) -> wtT[o][k*256+i] bf16 ---------------
__global__ __launch_bounds__(256) void k_wtT(const float* __restrict__ cw,
                                             unsigned short* __restrict__ wtT) {
  int o = blockIdx.x, k = blockIdx.y, i = threadIdx.x;
  wtT[o * 768 + k * 256 + i] = f2bf(cw[o * 768 + i * 3 + k]);
}

// ---------------- stage 0b: pw [k][n] -> pwT[n][k] bf16 --------------------------
__global__ __launch_bounds__(256) void k_pwT(const float* __restrict__ pw,
                                             unsigned short* __restrict__ pwT) {
  __shared__ float T[32][33];
  int n0 = blockIdx.x * 32;   // 8 blocks
  int k0 = blockIdx.y * 32;   // 32 blocks
  int tx = threadIdx.x & 31, ty = threadIdx.x >> 5;
#pragma unroll
  for (int i = 0; i < 4; i++)
    T[ty + i * 8][tx] = pw[(k0 + ty + i * 8) * P_ + n0 + tx];
  __syncthreads();
#pragma unroll
  for (int i = 0; i < 4; i++)
    pwT[(size_t)(n0 + ty + i * 8) * E_ + k0 + tx] = f2bf(T[tx][ty + i * 8]);
}

// ---------------- stage 0c: attn_w [k][j] -> awT[j][k] bf16 ----------------------
__global__ __launch_bounds__(256) void k_awT(const float* __restrict__ aw,
                                             unsigned short* __restrict__ awT) {
  __shared__ float T[32][33];
  int j0 = blockIdx.x * 32;   // 128 blocks
  int k0 = blockIdx.y * 32;   // 8 blocks
  int tx = threadIdx.x & 31, ty = threadIdx.x >> 5;
#pragma unroll
  for (int i = 0; i < 4; i++)
    T[ty + i * 8][tx] = aw[(k0 + ty + i * 8) * 4096 + j0 + tx];
  __syncthreads();
#pragma unroll
  for (int i = 0; i < 4; i++)
    awT[(size_t)(j0 + ty + i * 8) * 256 + k0 + tx] = f2bf(T[tx][ty + i * 8]);
}

// ---------------- zero Z (16K) + wB (16K) + repA (8K) floats, contiguous ---------
__global__ __launch_bounds__(256) void k_zero(float* __restrict__ p) {
  p[blockIdx.x * 256 + threadIdx.x] = 0.f;
}

// ---------------- stage 1: proj16 = bf16(x @ pw + pb)  (16384x1024x256) ----------
// block: 64 rows x 256 cols (grid 256). 4 waves, each 64 rows x 64 cols.
// __launch_bounds__(256,4): force <=128 unified regs -> 4 waves/SIMD residency.
__global__ __launch_bounds__(256, 4) void k_proj_mfma(const float* __restrict__ x,
                                                      const unsigned short* __restrict__ pwT,
                                                      const float* __restrict__ pb,
                                                      unsigned short* __restrict__ proj16) {
  __shared__ unsigned short As[16 * 64 * 8];  // (kk2*64 + row)*8, 16 KiB
  const int m0 = blockIdx.x * 64;
  const int t = threadIdx.x;
  const int w = t >> 6, lane = t & 63, ln31 = lane & 31, kh = lane >> 5;
  const int c0 = w * 64;

  f32x16 acc00, acc01, acc10, acc11;
#pragma unroll
  for (int r = 0; r < 16; r++) { acc00[r] = 0.f; acc01[r] = 0.f; acc10[r] = 0.f; acc11[r] = 0.f; }

  const unsigned short* bp0 = pwT + (size_t)(c0 + ln31) * E_ + kh * 8;
  const unsigned short* bp1 = bp0 + (size_t)32 * E_;

  for (int kc = 0; kc < E_; kc += 128) {
#pragma unroll
    for (int i = 0; i < 8; i++) {
      int c = t + i * 256;
      int row = c >> 5, pos = c & 31;
      float4 v = *(const float4*)(x + (size_t)(m0 + row) * E_ + kc + pos * 4);
      us4 h;
      h[0] = f2bf(v.x); h[1] = f2bf(v.y); h[2] = f2bf(v.z); h[3] = f2bf(v.w);
      *(us4*)&As[((pos >> 1) * 64 + row) * 8 + (pos & 1) * 4] = h;
    }
    __syncthreads();
#pragma unroll
    for (int kk = 0; kk < 8; kk++) {
      bf16x8 a0 = *(const bf16x8*)&As[((2 * kk + kh) * 64 + ln31) * 8];
      bf16x8 a1 = *(const bf16x8*)&As[((2 * kk + kh) * 64 + 32 + ln31) * 8];
      bf16x8 b0 = *(const bf16x8*)(bp0 + kc + kk * 16);
      bf16x8 b1 = *(const bf16x8*)(bp1 + kc + kk * 16);
      acc00 = __builtin_amdgcn_mfma_f32_32x32x16_bf16(a0, b0, acc00, 0, 0, 0);
      acc01 = __builtin_amdgcn_mfma_f32_32x32x16_bf16(a0, b1, acc01, 0, 0, 0);
      acc10 = __builtin_amdgcn_mfma_f32_32x32x16_bf16(a1, b0, acc10, 0, 0, 0);
      acc11 = __builtin_amdgcn_mfma_f32_32x32x16_bf16(a1, b1, acc11, 0, 0, 0);
    }
    __syncthreads();
  }
  float pb0 = pb[c0 + ln31], pb1 = pb[c0 + 32 + ln31];
#pragma unroll
  for (int r = 0; r < 16; r++) {
    int rl = (r & 3) + 8 * (r >> 2) + 4 * kh;
    size_t g0 = (size_t)(m0 + rl) * P_;
    size_t g1 = (size_t)(m0 + 32 + rl) * P_;
    proj16[g0 + c0 + ln31]      = f2bf(acc00[r] + pb0);
    proj16[g0 + c0 + 32 + ln31] = f2bf(acc01[r] + pb1);
    proj16[g1 + c0 + ln31]      = f2bf(acc10[r] + pb0);
    proj16[g1 + c0 + 32 + ln31] = f2bf(acc11[r] + pb1);
  }
}

// ---------------- stage 2: conv-as-3-shift-GEMM -> rep16 (16384x768x256) ---------
// block: 64 rows x 256 cols (grid 256). Stage 66 rows once; 3 shift-GEMMs (K=256).
__global__ __launch_bounds__(256, 4) void k_conv_mfma(const unsigned short* __restrict__ proj16,
                                                      const unsigned short* __restrict__ wtT,
                                                      const float* __restrict__ cb,
                                                      const int* __restrict__ seq,
                                                      unsigned short* __restrict__ rep16) {
  __shared__ unsigned short As[32 * 66 * 8];  // (kk2*66 + row)*8, 33 KiB
  const int m0 = blockIdx.x * 64;
  const int bb = m0 >> 9, s0 = m0 & 511;
  const int t = threadIdx.x;
  const int w = t >> 6, lane = t & 63, ln31 = lane & 31, kh = lane >> 5;
  const int c0 = w * 64;

#pragma unroll
  for (int i = 0; i < 9; i++) {
    int c = t + i * 256;
    if (c < 2112) {
      int row = c >> 5, kk2 = c & 31;
      us8 v = {0, 0, 0, 0, 0, 0, 0, 0};
      if (s0 + row <= 511)
        v = *(const us8*)(proj16 + (size_t)(bb * S_ + s0 + row) * P_ + kk2 * 8);
      *(us8*)&As[(kk2 * 66 + row) * 8] = v;
    }
  }
  __syncthreads();

  f32x16 acc00, acc01, acc10, acc11;
#pragma unroll
  for (int r = 0; r < 16; r++) { acc00[r] = 0.f; acc01[r] = 0.f; acc10[r] = 0.f; acc11[r] = 0.f; }

  const unsigned short* bbase0 = wtT + (size_t)(c0 + ln31) * 768 + kh * 8;
  const unsigned short* bbase1 = bbase0 + (size_t)32 * 768;

#pragma unroll
  for (int k = 0; k < 3; k++) {
#pragma unroll
    for (int kk = 0; kk < 16; kk++) {
      bf16x8 a0 = *(const bf16x8*)&As[((2 * kk + kh) * 66 + k + ln31) * 8];
      bf16x8 a1 = *(const bf16x8*)&As[((2 * kk + kh) * 66 + k + 32 + ln31) * 8];
      bf16x8 b0 = *(const bf16x8*)(bbase0 + k * 256 + kk * 16);
      bf16x8 b1 = *(const bf16x8*)(bbase1 + k * 256 + kk * 16);
      acc00 = __builtin_amdgcn_mfma_f32_32x32x16_bf16(a0, b0, acc00, 0, 0, 0);
      acc01 = __builtin_amdgcn_mfma_f32_32x32x16_bf16(a0, b1, acc01, 0, 0, 0);
      acc10 = __builtin_amdgcn_mfma_f32_32x32x16_bf16(a1, b0, acc10, 0, 0, 0);
      acc11 = __builtin_amdgcn_mfma_f32_32x32x16_bf16(a1, b1, acc11, 0, 0, 0);
    }
  }

  int l = seq[bb];
  float cb0 = cb[c0 + ln31], cb1 = cb[c0 + 32 + ln31];
#pragma unroll
  for (int r = 0; r < 16; r++) {
    int rl = (r & 3) + 8 * (r >> 2) + 4 * kh;
    int s_a = s0 + rl, s_b = s0 + 32 + rl;
    float ma = (s_a >= 1 && s_a <= 509 && s_a < l - 1) ? 1.f : 0.f;
    float mb = (s_b >= 1 && s_b <= 509 && s_b < l - 1) ? 1.f : 0.f;
    size_t g0 = (size_t)(m0 + rl) * P_;
    size_t g1 = (size_t)(m0 + 32 + rl) * P_;
    rep16[g0 + c0 + ln31]      = f2bf(fmaxf(acc00[r] + cb0, 0.f) * ma);
    rep16[g0 + c0 + 32 + ln31] = f2bf(fmaxf(acc01[r] + cb1, 0.f) * ma);
    rep16[g1 + c0 + ln31]      = f2bf(fmaxf(acc10[r] + cb0, 0.f) * mb);
    rep16[g1 + c0 + 32 + ln31] = f2bf(fmaxf(acc11[r] + cb1, 0.f) * mb);
  }
}

// ---------------- stage 3: MFMA logits + exp + h-fold + Z-fold -> E16 bf16 -------
// block: 64 rows x 128 q (grid 256x4). 4 waves, each 64 rows x 32 q — the R3
// structure (2 MFMA chains/wave), E16-bf16 store + fused Z.
// __launch_bounds__(256,4): <=128 unified regs -> 4 waves/SIMD (was 2).
__global__ __launch_bounds__(256, 4) void k_attn_mfma(const unsigned short* __restrict__ rep16,
                                                      const unsigned short* __restrict__ awT,
                                                      const float* __restrict__ ab,
                                                      unsigned short* __restrict__ E16,
                                                      float* __restrict__ Z) {
  __shared__ unsigned short As[64][264];
  const int m0 = blockIdx.x * 64;
  const int q0 = blockIdx.y * 128;
  const int t = threadIdx.x;
  const int w = t >> 6;
  const int lane = t & 63;
  const int ln31 = lane & 31;
  const int kh = lane >> 5;
  const int khalf = kh * 8;

  // stage A: 64 rows x 256 k (bf16) = 32 KB
#pragma unroll
  for (int i = 0; i < 8; i++) {
    int flat = i * 256 + t;
    int r = flat >> 5;
    int g = (flat & 31) * 8;
    us8 v = *(const us8*)(rep16 + (size_t)(m0 + r) * 256 + g);
    *(us8*)&As[r][g] = v;
  }
  __syncthreads();

  const int qcol = q0 + w * 32 + ln31;
  const unsigned short* bcol = awT + (size_t)qcol * 256 + khalf;

  float ef0[16], ef1[16];
#pragma unroll
  for (int r = 0; r < 16; r++) { ef0[r] = 0.f; ef1[r] = 0.f; }

  for (int h = 0; h < HH; h++) {
    const unsigned short* bh = bcol + (size_t)h * 512 * 256;
    f32x16 acc0, acc1;
#pragma unroll
    for (int r = 0; r < 16; r++) { acc0[r] = 0.f; acc1[r] = 0.f; }

#pragma unroll
    for (int kc = 0; kc < 256; kc += 16) {
      bf16x8 a0 = *(const bf16x8*)&As[ln31][kc + khalf];
      bf16x8 a1 = *(const bf16x8*)&As[32 + ln31][kc + khalf];
      bf16x8 b  = *(const bf16x8*)(bh + kc);
      acc0 = __builtin_amdgcn_mfma_f32_32x32x16_bf16(a0, b, acc0, 0, 0, 0);
      acc1 = __builtin_amdgcn_mfma_f32_32x32x16_bf16(a1, b, acc1, 0, 0, 0);
    }
    float bias = ab[h * 512 + qcol];
#pragma unroll
    for (int r = 0; r < 16; r++) {
      ef0[r] += __expf(acc0[r] + bias);
      ef1[r] += __expf(acc1[r] + bias);
    }
  }

  // store E16 (bf16)
#pragma unroll
  for (int r = 0; r < 16; r++) {
    int rl = (r & 3) + 8 * (r >> 2) + 4 * kh;
    E16[(size_t)(m0 + rl) * 512 + qcol]      = f2bf(ef0[r]);
    E16[(size_t)(m0 + 32 + rl) * 512 + qcol] = f2bf(ef1[r]);
  }

  // Z partial row-sums: butterfly over the 32 q-lanes of each half-wave
#pragma unroll
  for (int r = 0; r < 16; r++) {
    float z0 = ef0[r];
    float z1 = ef1[r];
#pragma unroll
    for (int st = 16; st >= 1; st >>= 1) {
      z0 += __shfl_xor(z0, st, 64);
      z1 += __shfl_xor(z1, st, 64);
    }
    if (ln31 == 0) {
      int rl = (r & 3) + 8 * (r >> 2) + 4 * kh;
      atomicAdd(&Z[m0 + rl], z0);
      atomicAdd(&Z[m0 + 32 + rl], z1);
    }
  }
}

// ---------------- stage 4: w[b,q] = (1/H) sum_s E16[b,s,q]/Z[b,s] ----------------
__global__ __launch_bounds__(512) void k_w(const unsigned short* __restrict__ E16,
                                           const float* __restrict__ Z,
                                           float* __restrict__ wB) {
  __shared__ float rZ[64];
  int b = blockIdx.x, c = blockIdx.y, t = threadIdx.x;
  int s0 = c * 64;
  if (t < 64) rZ[t] = 1.0f / Z[b * 512 + s0 + t];
  __syncthreads();
  float acc = 0.f;
#pragma unroll 8
  for (int s = 0; s < 64; s++)
    acc += bf2f(E16[(size_t)(b * 512 + s0 + s) * 512 + t]) * rZ[s];
  atomicAdd(&wB[b * 512 + t], acc * (1.0f / HH));
}

// ---------------- stage 5a: repA[b,p] = sum_q w[b,q] * rep16[b,q,p] --------------
__global__ __launch_bounds__(256) void k_final_a(const unsigned short* __restrict__ rep16,
                                                 const float* __restrict__ wB,
                                                 float* __restrict__ repA) {
  __shared__ float wS[64];
  int b = blockIdx.x, qc = blockIdx.y, t = threadIdx.x;
  if (t < 64) wS[t] = wB[b * 512 + qc * 64 + t];
  __syncthreads();
  float acc = 0.f;
  const unsigned short* base = rep16 + (size_t)(b * 512 + qc * 64) * 256 + t;
#pragma unroll 8
  for (int q = 0; q < 64; q++) acc += wS[q] * bf2f(base[(size_t)q * 256]);
  atomicAdd(&repA[b * 256 + t], acc);
}

// ---------------- stage 5b: heads -> probs + argmax ------------------------------
__global__ __launch_bounds__(128) void k_final_b(const float* __restrict__ repA,
                                                 const float* __restrict__ c1w,
                                                 const float* __restrict__ c1b,
                                                 const float* __restrict__ c2w,
                                                 const float* __restrict__ c2b,
                                                 float* __restrict__ out) {
  __shared__ float hS[128];
  __shared__ float clsS[2];
  int b = blockIdx.x, t = threadIdx.x;
  float acc = c1b[t];
  for (int p = 0; p < 256; p++) acc += repA[b * 256 + p] * c1w[p * 128 + t];
  hS[t] = acc > 0.f ? acc : 0.01f * acc;
  __syncthreads();
  if (t < 2) {
    float a2 = c2b[t];
    for (int j = 0; j < 128; j++) a2 += hS[j] * c2w[j * 2 + t];
    clsS[t] = a2;
  }
  __syncthreads();
  if (t == 0) {
    float c0 = clsS[0], c1 = clsS[1];
    float m = fmaxf(c0, c1);
    float e0 = __expf(c0 - m), e1 = __expf(c1 - m);
    float inv = 1.0f / (e0 + e1);
    float p0 = e0 * inv, p1 = e1 * inv;
    out[b * 2 + 0] = p0;
    out[b * 2 + 1] = p1;
    out[B_ * 2 + b] = (p1 > p0) ? 1.0f : 0.0f;
  }
}

extern "C" void kernel_launch(void* const* d_in, const int* in_sizes, int n_in,
                              void* d_out, int out_size, void* d_ws, size_t ws_size,
                              hipStream_t stream) {
  const float* x   = (const float*)d_in[0];
  const int*   seq = (const int*)d_in[1];
  const float* pw  = (const float*)d_in[2];
  const float* pb  = (const float*)d_in[3];
  const float* cw  = (const float*)d_in[4];
  const float* cb  = (const float*)d_in[5];
  const float* aw  = (const float*)d_in[6];
  const float* ab  = (const float*)d_in[7];
  const float* c1w = (const float*)d_in[8];
  const float* c1b = (const float*)d_in[9];
  const float* c2w = (const float*)d_in[10];
  const float* c2b = (const float*)d_in[11];
  float* out = (float*)d_out;

  char* ws = (char*)d_ws;
  // proj16 (8 MiB) overlaps E16 (16 MiB): proj16 dies (k_conv) before E16 written
  unsigned short* proj16 = (unsigned short*)(ws);
  unsigned short* E16    = (unsigned short*)(ws);                     // 16 MiB @ 0
  unsigned short* rep16  = (unsigned short*)(ws + (size_t)16777216);  // 8 MiB
  unsigned short* pwT    = (unsigned short*)(ws + (size_t)25165824);  // 512 KiB
  unsigned short* wtT    = (unsigned short*)(ws + (size_t)25690112);  // 384 KiB
  unsigned short* awT    = (unsigned short*)(ws + (size_t)26083328);  // 2 MiB
  float*          Z      = (float*)(ws + (size_t)28180480);           // 64 KiB
  float*          wB     = (float*)(ws + (size_t)28246016);           // 64 KiB
  float*          repA   = (float*)(ws + (size_t)28311552);           // 32 KiB

  k_zero<<<160, 256, 0, stream>>>(Z);  // Z + wB + repA contiguous (40960 floats)
  k_wtT<<<dim3(256, 3), 256, 0, stream>>>(cw, wtT);
  k_pwT<<<dim3(8, 32), 256, 0, stream>>>(pw, pwT);
  k_awT<<<dim3(128, 8), 256, 0, stream>>>(aw, awT);
  k_proj_mfma<<<256, 256, 0, stream>>>(x, pwT, pb, proj16);
  k_conv_mfma<<<256, 256, 0, stream>>>(proj16, wtT, cb, seq, rep16);
  k_attn_mfma<<<dim3(256, 4), 256, 0, stream>>>(rep16, awT, ab, E16, Z);
  k_w<<<dim3(32, 8), 512, 0, stream>>>(E16, Z, wB);
  k_final_a<<<dim3(32, 8), 256, 0, stream>>>(rep16, wB, repA);
  k_final_b<<<32, 128, 0, stream>>>(repA, c1w, c1b, c2w, c2b, out);
}

// Round 7
// 252.167 us; speedup vs baseline: 1.4670x; 1.4670x over previous
//
#include <hip/hip_runtime.h>

#define B_ 32
#define S_ 512
#define E_ 1024
#define P_ 256
#define HH 8
// rows = B*S = 16384

typedef __attribute__((ext_vector_type(8))) short bf16x8;
typedef __attribute__((ext_vector_type(8))) unsigned short us8;
typedef __attribute__((ext_vector_type(4))) unsigned short us4;
typedef __attribute__((ext_vector_type(16))) float f32x16;

static __device__ __forceinline__ unsigned short f2bf(float f) {
  union { float f; unsigned int u; } v;
  v.f = f;
  unsigned int r = (v.u + 0x7FFFu + ((v.u >> 16) & 1u)) >> 16;
  return (unsigned short)r;
}
static __device__ __forceinline__ float bf2f(unsigned short u) {
  union { unsigned int u; float f; } v;
  v.u = ((unsigned int)u) << 16;
  return v.f;
}

// ---------------- stage 0a: conv_w (O,I,K) -> wtT16[o][k*256+i] bf16 -------------
__global__ __launch_bounds__(256) void k_wtT(const float* __restrict__ cw,
                                             unsigned short* __restrict__ wtT) {
  int o = blockIdx.x, k = blockIdx.y, i = threadIdx.x;
  wtT[o * 768 + k * 256 + i] = f2bf(cw[o * 768 + i * 3 + k]);
}

// ---------------- stage 0b: pw [k][n] -> pwT[n][k] bf16 --------------------------
__global__ __launch_bounds__(256) void k_pwT(const float* __restrict__ pw,
                                             unsigned short* __restrict__ pwT) {
  __shared__ float T[32][33];
  int n0 = blockIdx.x * 32;   // 8 blocks
  int k0 = blockIdx.y * 32;   // 32 blocks
  int tx = threadIdx.x & 31, ty = threadIdx.x >> 5;
#pragma unroll
  for (int i = 0; i < 4; i++)
    T[ty + i * 8][tx] = pw[(k0 + ty + i * 8) * P_ + n0 + tx];
  __syncthreads();
#pragma unroll
  for (int i = 0; i < 4; i++)
    pwT[(size_t)(n0 + ty + i * 8) * E_ + k0 + tx] = f2bf(T[tx][ty + i * 8]);
}

// ---------------- stage 0c: attn_w [k][j] -> awT[j][k] bf16 ----------------------
__global__ __launch_bounds__(256) void k_awT(const float* __restrict__ aw,
                                             unsigned short* __restrict__ awT) {
  __shared__ float T[32][33];
  int j0 = blockIdx.x * 32;   // 128 blocks
  int k0 = blockIdx.y * 32;   // 8 blocks
  int tx = threadIdx.x & 31, ty = threadIdx.x >> 5;
#pragma unroll
  for (int i = 0; i < 4; i++)
    T[ty + i * 8][tx] = aw[(k0 + ty + i * 8) * 4096 + j0 + tx];
  __syncthreads();
#pragma unroll
  for (int i = 0; i < 4; i++)
    awT[(size_t)(j0 + ty + i * 8) * 256 + k0 + tx] = f2bf(T[tx][ty + i * 8]);
}

// ---------------- stage 0d: fragment-native swizzle ------------------------------
// src: bf16 [N][K] row-major (N = 32*ngrps). dst blocks of 512 shorts per
// (grp, kc): dst[(grp*NK + kc)*512 + l*8 + j] = src[grp*32 + (l&31)][kc*16 + (l>>5)*8 + j]
// so a wave's B-fragment load at (grp,kc) is base + lane*16B — fully coalesced.
__global__ __launch_bounds__(256) void k_swz(const unsigned short* __restrict__ src,
                                             unsigned short* __restrict__ dst,
                                             int K, int NK) {
  int g = blockIdx.x, kc = blockIdx.y * 4 + (threadIdx.x >> 6);
  int l = threadIdx.x & 63;
  us8 v = *(const us8*)(src + (size_t)(g * 32 + (l & 31)) * K + kc * 16 + (l >> 5) * 8);
  *(us8*)(dst + ((size_t)g * NK + kc) * 512 + l * 8) = v;
}

// ---------------- zero Z (16K) + wB (16K) + repA (8K) floats, contiguous ---------
__global__ __launch_bounds__(256) void k_zero(float* __restrict__ p) {
  p[blockIdx.x * 256 + threadIdx.x] = 0.f;
}

// ---------------- stage 1: proj16 = bf16(x @ pw + pb)  (16384x1024x256) ----------
// block: 64 rows x 256 cols (grid 256). 4 waves, each 64 rows x 64 cols.
// B register-direct from swizzled pwB: every load is lane-contiguous 1 KB.
__global__ __launch_bounds__(256) void k_proj_mfma(const float* __restrict__ x,
                                                   const unsigned short* __restrict__ pwB,
                                                   const float* __restrict__ pb,
                                                   unsigned short* __restrict__ proj16) {
  __shared__ unsigned short As[16 * 64 * 8];  // (kk2*64 + row)*8, 16 KiB
  const int m0 = blockIdx.x * 64;
  const int t = threadIdx.x;
  const int w = t >> 6, lane = t & 63, ln31 = lane & 31, kh = lane >> 5;
  const int c0 = w * 64;

  f32x16 acc00, acc01, acc10, acc11;
#pragma unroll
  for (int r = 0; r < 16; r++) { acc00[r] = 0.f; acc01[r] = 0.f; acc10[r] = 0.f; acc11[r] = 0.f; }

  // ngrp = 2w and 2w+1; block stride 512, NK=64
  const unsigned short* bp0 = pwB + (size_t)(2 * w) * 64 * 512 + lane * 8;
  const unsigned short* bp1 = bp0 + (size_t)64 * 512;

  for (int kc = 0; kc < E_; kc += 128) {
#pragma unroll
    for (int i = 0; i < 8; i++) {
      int c = t + i * 256;
      int row = c >> 5, pos = c & 31;
      float4 v = *(const float4*)(x + (size_t)(m0 + row) * E_ + kc + pos * 4);
      us4 h;
      h[0] = f2bf(v.x); h[1] = f2bf(v.y); h[2] = f2bf(v.z); h[3] = f2bf(v.w);
      *(us4*)&As[((pos >> 1) * 64 + row) * 8 + (pos & 1) * 4] = h;
    }
    __syncthreads();
    const int kcs = kc >> 4;
#pragma unroll
    for (int kk = 0; kk < 8; kk++) {
      bf16x8 a0 = *(const bf16x8*)&As[((2 * kk + kh) * 64 + ln31) * 8];
      bf16x8 a1 = *(const bf16x8*)&As[((2 * kk + kh) * 64 + 32 + ln31) * 8];
      bf16x8 b0 = *(const bf16x8*)(bp0 + (size_t)(kcs + kk) * 512);
      bf16x8 b1 = *(const bf16x8*)(bp1 + (size_t)(kcs + kk) * 512);
      acc00 = __builtin_amdgcn_mfma_f32_32x32x16_bf16(a0, b0, acc00, 0, 0, 0);
      acc01 = __builtin_amdgcn_mfma_f32_32x32x16_bf16(a0, b1, acc01, 0, 0, 0);
      acc10 = __builtin_amdgcn_mfma_f32_32x32x16_bf16(a1, b0, acc10, 0, 0, 0);
      acc11 = __builtin_amdgcn_mfma_f32_32x32x16_bf16(a1, b1, acc11, 0, 0, 0);
    }
    __syncthreads();
  }
  float pb0 = pb[c0 + ln31], pb1 = pb[c0 + 32 + ln31];
#pragma unroll
  for (int r = 0; r < 16; r++) {
    int rl = (r & 3) + 8 * (r >> 2) + 4 * kh;
    size_t g0 = (size_t)(m0 + rl) * P_;
    size_t g1 = (size_t)(m0 + 32 + rl) * P_;
    proj16[g0 + c0 + ln31]      = f2bf(acc00[r] + pb0);
    proj16[g0 + c0 + 32 + ln31] = f2bf(acc01[r] + pb1);
    proj16[g1 + c0 + ln31]      = f2bf(acc10[r] + pb0);
    proj16[g1 + c0 + 32 + ln31] = f2bf(acc11[r] + pb1);
  }
}

// ---------------- stage 2: conv-as-3-shift-GEMM -> rep16 (16384x768x256) ---------
// block: 64 rows x 256 cols (grid 256). B register-direct from swizzled wtB.
__global__ __launch_bounds__(256) void k_conv_mfma(const unsigned short* __restrict__ proj16,
                                                   const unsigned short* __restrict__ wtB,
                                                   const float* __restrict__ cb,
                                                   const int* __restrict__ seq,
                                                   unsigned short* __restrict__ rep16) {
  __shared__ unsigned short As[32 * 66 * 8];  // (kk2*66 + row)*8, 33 KiB
  const int m0 = blockIdx.x * 64;
  const int bb = m0 >> 9, s0 = m0 & 511;
  const int t = threadIdx.x;
  const int w = t >> 6, lane = t & 63, ln31 = lane & 31, kh = lane >> 5;
  const int c0 = w * 64;

#pragma unroll
  for (int i = 0; i < 9; i++) {
    int c = t + i * 256;
    if (c < 2112) {
      int row = c >> 5, kk2 = c & 31;
      us8 v = {0, 0, 0, 0, 0, 0, 0, 0};
      if (s0 + row <= 511)
        v = *(const us8*)(proj16 + (size_t)(bb * S_ + s0 + row) * P_ + kk2 * 8);
      *(us8*)&As[(kk2 * 66 + row) * 8] = v;
    }
  }
  __syncthreads();

  f32x16 acc00, acc01, acc10, acc11;
#pragma unroll
  for (int r = 0; r < 16; r++) { acc00[r] = 0.f; acc01[r] = 0.f; acc10[r] = 0.f; acc11[r] = 0.f; }

  // ogrp = 2w and 2w+1; NK=48
  const unsigned short* bb0 = wtB + (size_t)(2 * w) * 48 * 512 + lane * 8;
  const unsigned short* bb1 = bb0 + (size_t)48 * 512;

#pragma unroll
  for (int k = 0; k < 3; k++) {
#pragma unroll
    for (int kk = 0; kk < 16; kk++) {
      bf16x8 a0 = *(const bf16x8*)&As[((2 * kk + kh) * 66 + k + ln31) * 8];
      bf16x8 a1 = *(const bf16x8*)&As[((2 * kk + kh) * 66 + k + 32 + ln31) * 8];
      bf16x8 b0 = *(const bf16x8*)(bb0 + (size_t)(k * 16 + kk) * 512);
      bf16x8 b1 = *(const bf16x8*)(bb1 + (size_t)(k * 16 + kk) * 512);
      acc00 = __builtin_amdgcn_mfma_f32_32x32x16_bf16(a0, b0, acc00, 0, 0, 0);
      acc01 = __builtin_amdgcn_mfma_f32_32x32x16_bf16(a0, b1, acc01, 0, 0, 0);
      acc10 = __builtin_amdgcn_mfma_f32_32x32x16_bf16(a1, b0, acc10, 0, 0, 0);
      acc11 = __builtin_amdgcn_mfma_f32_32x32x16_bf16(a1, b1, acc11, 0, 0, 0);
    }
  }

  int l = seq[bb];
  float cb0 = cb[c0 + ln31], cb1 = cb[c0 + 32 + ln31];
#pragma unroll
  for (int r = 0; r < 16; r++) {
    int rl = (r & 3) + 8 * (r >> 2) + 4 * kh;
    int s_a = s0 + rl, s_b = s0 + 32 + rl;
    float ma = (s_a >= 1 && s_a <= 509 && s_a < l - 1) ? 1.f : 0.f;
    float mb = (s_b >= 1 && s_b <= 509 && s_b < l - 1) ? 1.f : 0.f;
    size_t g0 = (size_t)(m0 + rl) * P_;
    size_t g1 = (size_t)(m0 + 32 + rl) * P_;
    rep16[g0 + c0 + ln31]      = f2bf(fmaxf(acc00[r] + cb0, 0.f) * ma);
    rep16[g0 + c0 + 32 + ln31] = f2bf(fmaxf(acc01[r] + cb1, 0.f) * ma);
    rep16[g1 + c0 + ln31]      = f2bf(fmaxf(acc10[r] + cb0, 0.f) * mb);
    rep16[g1 + c0 + 32 + ln31] = f2bf(fmaxf(acc11[r] + cb1, 0.f) * mb);
  }
}

// ---------------- stage 3: MFMA logits + exp + h-fold + Z-fold -> E16 bf16 -------
// block: 64 rows x 128 q (grid 256x4). 4 waves, each 64 rows x 32 q (R3 form).
// B register-direct from swizzled awB: grp = h*16 + (q0>>5)+w, 16 kc-blocks of
// 512 shorts; every load is base + lane*16B (contiguous 1 KB / instr).
__global__ __launch_bounds__(256) void k_attn_mfma(const unsigned short* __restrict__ rep16,
                                                   const unsigned short* __restrict__ awB,
                                                   const float* __restrict__ ab,
                                                   unsigned short* __restrict__ E16,
                                                   float* __restrict__ Z) {
  __shared__ unsigned short As[64][264];
  const int m0 = blockIdx.x * 64;
  const int q0 = blockIdx.y * 128;
  const int t = threadIdx.x;
  const int w = t >> 6;
  const int lane = t & 63;
  const int ln31 = lane & 31;
  const int kh = lane >> 5;
  const int khalf = kh * 8;

  // stage A: 64 rows x 256 k (bf16) = 32 KB
#pragma unroll
  for (int i = 0; i < 8; i++) {
    int flat = i * 256 + t;
    int r = flat >> 5;
    int g = (flat & 31) * 8;
    us8 v = *(const us8*)(rep16 + (size_t)(m0 + r) * 256 + g);
    *(us8*)&As[r][g] = v;
  }
  __syncthreads();

  const int qgidx = (q0 >> 5) + w;         // q-group 0..15
  const int qcol = qgidx * 32 + ln31;
  const unsigned short* bg = awB + (size_t)qgidx * 16 * 512 + lane * 8;

  float ef0[16], ef1[16];
#pragma unroll
  for (int r = 0; r < 16; r++) { ef0[r] = 0.f; ef1[r] = 0.f; }

  for (int h = 0; h < HH; h++) {
    const unsigned short* bh = bg + (size_t)h * 16 * 16 * 512;  // grp stride h*16 blocks
    f32x16 acc0, acc1;
#pragma unroll
    for (int r = 0; r < 16; r++) { acc0[r] = 0.f; acc1[r] = 0.f; }

#pragma unroll
    for (int kc = 0; kc < 16; kc++) {
      bf16x8 a0 = *(const bf16x8*)&As[ln31][kc * 16 + khalf];
      bf16x8 a1 = *(const bf16x8*)&As[32 + ln31][kc * 16 + khalf];
      bf16x8 b  = *(const bf16x8*)(bh + (size_t)kc * 512);
      acc0 = __builtin_amdgcn_mfma_f32_32x32x16_bf16(a0, b, acc0, 0, 0, 0);
      acc1 = __builtin_amdgcn_mfma_f32_32x32x16_bf16(a1, b, acc1, 0, 0, 0);
    }
    float bias = ab[h * 512 + qcol];
#pragma unroll
    for (int r = 0; r < 16; r++) {
      ef0[r] += __expf(acc0[r] + bias);
      ef1[r] += __expf(acc1[r] + bias);
    }
  }

  // store E16 (bf16)
#pragma unroll
  for (int r = 0; r < 16; r++) {
    int rl = (r & 3) + 8 * (r >> 2) + 4 * kh;
    E16[(size_t)(m0 + rl) * 512 + qcol]      = f2bf(ef0[r]);
    E16[(size_t)(m0 + 32 + rl) * 512 + qcol] = f2bf(ef1[r]);
  }

  // Z partial row-sums: butterfly over the 32 q-lanes of each half-wave
#pragma unroll
  for (int r = 0; r < 16; r++) {
    float z0 = ef0[r];
    float z1 = ef1[r];
#pragma unroll
    for (int st = 16; st >= 1; st >>= 1) {
      z0 += __shfl_xor(z0, st, 64);
      z1 += __shfl_xor(z1, st, 64);
    }
    if (ln31 == 0) {
      int rl = (r & 3) + 8 * (r >> 2) + 4 * kh;
      atomicAdd(&Z[m0 + rl], z0);
      atomicAdd(&Z[m0 + 32 + rl], z1);
    }
  }
}

// ---------------- stage 4: w[b,q] = (1/H) sum_s E16[b,s,q]/Z[b,s] ----------------
__global__ __launch_bounds__(512) void k_w(const unsigned short* __restrict__ E16,
                                           const float* __restrict__ Z,
                                           float* __restrict__ wB) {
  __shared__ float rZ[64];
  int b = blockIdx.x, c = blockIdx.y, t = threadIdx.x;
  int s0 = c * 64;
  if (t < 64) rZ[t] = 1.0f / Z[b * 512 + s0 + t];
  __syncthreads();
  float acc = 0.f;
#pragma unroll 8
  for (int s = 0; s < 64; s++)
    acc += bf2f(E16[(size_t)(b * 512 + s0 + s) * 512 + t]) * rZ[s];
  atomicAdd(&wB[b * 512 + t], acc * (1.0f / HH));
}

// ---------------- stage 5a: repA[b,p] = sum_q w[b,q] * rep16[b,q,p] --------------
__global__ __launch_bounds__(256) void k_final_a(const unsigned short* __restrict__ rep16,
                                                 const float* __restrict__ wB,
                                                 float* __restrict__ repA) {
  __shared__ float wS[64];
  int b = blockIdx.x, qc = blockIdx.y, t = threadIdx.x;
  if (t < 64) wS[t] = wB[b * 512 + qc * 64 + t];
  __syncthreads();
  float acc = 0.f;
  const unsigned short* base = rep16 + (size_t)(b * 512 + qc * 64) * 256 + t;
#pragma unroll 8
  for (int q = 0; q < 64; q++) acc += wS[q] * bf2f(base[(size_t)q * 256]);
  atomicAdd(&repA[b * 256 + t], acc);
}

// ---------------- stage 5b: heads -> probs + argmax ------------------------------
__global__ __launch_bounds__(128) void k_final_b(const float* __restrict__ repA,
                                                 const float* __restrict__ c1w,
                                                 const float* __restrict__ c1b,
                                                 const float* __restrict__ c2w,
                                                 const float* __restrict__ c2b,
                                                 float* __restrict__ out) {
  __shared__ float hS[128];
  __shared__ float clsS[2];
  int b = blockIdx.x, t = threadIdx.x;
  float acc = c1b[t];
  for (int p = 0; p < 256; p++) acc += repA[b * 256 + p] * c1w[p * 128 + t];
  hS[t] = acc > 0.f ? acc : 0.01f * acc;
  __syncthreads();
  if (t < 2) {
    float a2 = c2b[t];
    for (int j = 0; j < 128; j++) a2 += hS[j] * c2w[j * 2 + t];
    clsS[t] = a2;
  }
  __syncthreads();
  if (t == 0) {
    float c0 = clsS[0], c1 = clsS[1];
    float m = fmaxf(c0, c1);
    float e0 = __expf(c0 - m), e1 = __expf(c1 - m);
    float inv = 1.0f / (e0 + e1);
    float p0 = e0 * inv, p1 = e1 * inv;
    out[b * 2 + 0] = p0;
    out[b * 2 + 1] = p1;
    out[B_ * 2 + b] = (p1 > p0) ? 1.0f : 0.0f;
  }
}

extern "C" void kernel_launch(void* const* d_in, const int* in_sizes, int n_in,
                              void* d_out, int out_size, void* d_ws, size_t ws_size,
                              hipStream_t stream) {
  const float* x   = (const float*)d_in[0];
  const int*   seq = (const int*)d_in[1];
  const float* pw  = (const float*)d_in[2];
  const float* pb  = (const float*)d_in[3];
  const float* cw  = (const float*)d_in[4];
  const float* cb  = (const float*)d_in[5];
  const float* aw  = (const float*)d_in[6];
  const float* ab  = (const float*)d_in[7];
  const float* c1w = (const float*)d_in[8];
  const float* c1b = (const float*)d_in[9];
  const float* c2w = (const float*)d_in[10];
  const float* c2b = (const float*)d_in[11];
  float* out = (float*)d_out;

  char* ws = (char*)d_ws;
  // proj16 (8 MiB) overlaps E16 (16 MiB): proj16 dies (k_conv) before E16 written
  unsigned short* proj16 = (unsigned short*)(ws);
  unsigned short* E16    = (unsigned short*)(ws);                     // 16 MiB @ 0
  unsigned short* rep16  = (unsigned short*)(ws + (size_t)16777216);  // 8 MiB
  unsigned short* pwT    = (unsigned short*)(ws + (size_t)25165824);  // 512 KiB
  unsigned short* wtT    = (unsigned short*)(ws + (size_t)25690112);  // 384 KiB
  unsigned short* awT    = (unsigned short*)(ws + (size_t)26083328);  // 2 MiB
  float*          Z      = (float*)(ws + (size_t)28180480);           // 64 KiB
  float*          wB     = (float*)(ws + (size_t)28246016);           // 64 KiB
  float*          repA   = (float*)(ws + (size_t)28311552);           // 32 KiB
  unsigned short* awB    = (unsigned short*)(ws + (size_t)28377088);  // 2 MiB swizzled
  unsigned short* pwB    = (unsigned short*)(ws + (size_t)30474240);  // 512 KiB swizzled
  unsigned short* wtB    = (unsigned short*)(ws + (size_t)30998528);  // 384 KiB swizzled

  k_zero<<<160, 256, 0, stream>>>(Z);  // Z + wB + repA contiguous (40960 floats)
  k_wtT<<<dim3(256, 3), 256, 0, stream>>>(cw, wtT);
  k_pwT<<<dim3(8, 32), 256, 0, stream>>>(pw, pwT);
  k_awT<<<dim3(128, 8), 256, 0, stream>>>(aw, awT);
  // fragment-native repack: grp count x NK/4
  k_swz<<<dim3(128, 4), 256, 0, stream>>>(awT, awB, 256, 16);
  k_swz<<<dim3(8, 16), 256, 0, stream>>>(pwT, pwB, 1024, 64);
  k_swz<<<dim3(8, 12), 256, 0, stream>>>(wtT, wtB, 768, 48);

  k_proj_mfma<<<256, 256, 0, stream>>>(x, pwB, pb, proj16);
  k_conv_mfma<<<256, 256, 0, stream>>>(proj16, wtB, cb, seq, rep16);
  k_attn_mfma<<<dim3(256, 4), 256, 0, stream>>>(rep16, awB, ab, E16, Z);
  k_w<<<dim3(32, 8), 512, 0, stream>>>(E16, Z, wB);
  k_final_a<<<dim3(32, 8), 256, 0, stream>>>(rep16, wB, repA);
  k_final_b<<<32, 128, 0, stream>>>(repA, c1w, c1b, c2w, c2b, out);
}

// Round 8
// 249.543 us; speedup vs baseline: 1.4824x; 1.0105x over previous
//
#include <hip/hip_runtime.h>

#define B_ 32
#define S_ 512
#define E_ 1024
#define P_ 256
#define HH 8
// rows = B*S = 16384

typedef __attribute__((ext_vector_type(8))) short bf16x8;
typedef __attribute__((ext_vector_type(8))) unsigned short us8;
typedef __attribute__((ext_vector_type(4))) unsigned short us4;
typedef __attribute__((ext_vector_type(16))) float f32x16;

static __device__ __forceinline__ unsigned short f2bf(float f) {
  union { float f; unsigned int u; } v;
  v.f = f;
  unsigned int r = (v.u + 0x7FFFu + ((v.u >> 16) & 1u)) >> 16;
  return (unsigned short)r;
}
static __device__ __forceinline__ float bf2f(unsigned short u) {
  union { unsigned int u; float f; } v;
  v.u = ((unsigned int)u) << 16;
  return v.f;
}

// ---------------- stage 0a: conv_w (O,I,K) -> wtT16[o][k*256+i] bf16 -------------
__global__ __launch_bounds__(256) void k_wtT(const float* __restrict__ cw,
                                             unsigned short* __restrict__ wtT) {
  int o = blockIdx.x, k = blockIdx.y, i = threadIdx.x;
  wtT[o * 768 + k * 256 + i] = f2bf(cw[o * 768 + i * 3 + k]);
}

// ---------------- stage 0b: pw [k][n] -> pwT[n][k] bf16 --------------------------
__global__ __launch_bounds__(256) void k_pwT(const float* __restrict__ pw,
                                             unsigned short* __restrict__ pwT) {
  __shared__ float T[32][33];
  int n0 = blockIdx.x * 32;   // 8 blocks
  int k0 = blockIdx.y * 32;   // 32 blocks
  int tx = threadIdx.x & 31, ty = threadIdx.x >> 5;
#pragma unroll
  for (int i = 0; i < 4; i++)
    T[ty + i * 8][tx] = pw[(k0 + ty + i * 8) * P_ + n0 + tx];
  __syncthreads();
#pragma unroll
  for (int i = 0; i < 4; i++)
    pwT[(size_t)(n0 + ty + i * 8) * E_ + k0 + tx] = f2bf(T[tx][ty + i * 8]);
}

// ---------------- stage 0c: attn_w [k][j] -> awT[j][k] bf16 ----------------------
__global__ __launch_bounds__(256) void k_awT(const float* __restrict__ aw,
                                             unsigned short* __restrict__ awT) {
  __shared__ float T[32][33];
  int j0 = blockIdx.x * 32;   // 128 blocks
  int k0 = blockIdx.y * 32;   // 8 blocks
  int tx = threadIdx.x & 31, ty = threadIdx.x >> 5;
#pragma unroll
  for (int i = 0; i < 4; i++)
    T[ty + i * 8][tx] = aw[(k0 + ty + i * 8) * 4096 + j0 + tx];
  __syncthreads();
#pragma unroll
  for (int i = 0; i < 4; i++)
    awT[(size_t)(j0 + ty + i * 8) * 256 + k0 + tx] = f2bf(T[tx][ty + i * 8]);
}

// ---------------- stage 0d: fragment-native swizzle ------------------------------
// src: bf16 [N][K] row-major (N = 32*ngrps). dst blocks of 512 shorts per
// (grp, kc): dst[(grp*NK + kc)*512 + l*8 + j] = src[grp*32 + (l&31)][kc*16 + (l>>5)*8 + j]
// so a wave's MFMA-fragment load at (grp,kc) is base + lane*16B — fully coalesced.
__global__ __launch_bounds__(256) void k_swz(const unsigned short* __restrict__ src,
                                             unsigned short* __restrict__ dst,
                                             int K, int NK) {
  int g = blockIdx.x, kc = blockIdx.y * 4 + (threadIdx.x >> 6);
  int l = threadIdx.x & 63;
  us8 v = *(const us8*)(src + (size_t)(g * 32 + (l & 31)) * K + kc * 16 + (l >> 5) * 8);
  *(us8*)(dst + ((size_t)g * NK + kc) * 512 + l * 8) = v;
}

// ---------------- zero Z (16K) + wB (16K) + repA (8K) floats, contiguous ---------
__global__ __launch_bounds__(256) void k_zero(float* __restrict__ p) {
  p[blockIdx.x * 256 + threadIdx.x] = 0.f;
}

// ---------------- stage 1: proj16 = bf16(x @ pw + pb)  (16384x1024x256) ----------
// block: 64 rows x 256 cols (grid 256). 4 waves, each 64 rows x 64 cols.
// B register-direct from swizzled pwB: every load is lane-contiguous 1 KB.
__global__ __launch_bounds__(256) void k_proj_mfma(const float* __restrict__ x,
                                                   const unsigned short* __restrict__ pwB,
                                                   const float* __restrict__ pb,
                                                   unsigned short* __restrict__ proj16) {
  __shared__ unsigned short As[16 * 64 * 8];  // (kk2*64 + row)*8, 16 KiB
  const int m0 = blockIdx.x * 64;
  const int t = threadIdx.x;
  const int w = t >> 6, lane = t & 63, ln31 = lane & 31, kh = lane >> 5;
  const int c0 = w * 64;

  f32x16 acc00, acc01, acc10, acc11;
#pragma unroll
  for (int r = 0; r < 16; r++) { acc00[r] = 0.f; acc01[r] = 0.f; acc10[r] = 0.f; acc11[r] = 0.f; }

  // ngrp = 2w and 2w+1; block stride 512, NK=64
  const unsigned short* bp0 = pwB + (size_t)(2 * w) * 64 * 512 + lane * 8;
  const unsigned short* bp1 = bp0 + (size_t)64 * 512;

  for (int kc = 0; kc < E_; kc += 128) {
#pragma unroll
    for (int i = 0; i < 8; i++) {
      int c = t + i * 256;
      int row = c >> 5, pos = c & 31;
      float4 v = *(const float4*)(x + (size_t)(m0 + row) * E_ + kc + pos * 4);
      us4 h;
      h[0] = f2bf(v.x); h[1] = f2bf(v.y); h[2] = f2bf(v.z); h[3] = f2bf(v.w);
      *(us4*)&As[((pos >> 1) * 64 + row) * 8 + (pos & 1) * 4] = h;
    }
    __syncthreads();
    const int kcs = kc >> 4;
#pragma unroll
    for (int kk = 0; kk < 8; kk++) {
      bf16x8 a0 = *(const bf16x8*)&As[((2 * kk + kh) * 64 + ln31) * 8];
      bf16x8 a1 = *(const bf16x8*)&As[((2 * kk + kh) * 64 + 32 + ln31) * 8];
      bf16x8 b0 = *(const bf16x8*)(bp0 + (size_t)(kcs + kk) * 512);
      bf16x8 b1 = *(const bf16x8*)(bp1 + (size_t)(kcs + kk) * 512);
      acc00 = __builtin_amdgcn_mfma_f32_32x32x16_bf16(a0, b0, acc00, 0, 0, 0);
      acc01 = __builtin_amdgcn_mfma_f32_32x32x16_bf16(a0, b1, acc01, 0, 0, 0);
      acc10 = __builtin_amdgcn_mfma_f32_32x32x16_bf16(a1, b0, acc10, 0, 0, 0);
      acc11 = __builtin_amdgcn_mfma_f32_32x32x16_bf16(a1, b1, acc11, 0, 0, 0);
    }
    __syncthreads();
  }
  float pb0 = pb[c0 + ln31], pb1 = pb[c0 + 32 + ln31];
#pragma unroll
  for (int r = 0; r < 16; r++) {
    int rl = (r & 3) + 8 * (r >> 2) + 4 * kh;
    size_t g0 = (size_t)(m0 + rl) * P_;
    size_t g1 = (size_t)(m0 + 32 + rl) * P_;
    proj16[g0 + c0 + ln31]      = f2bf(acc00[r] + pb0);
    proj16[g0 + c0 + 32 + ln31] = f2bf(acc01[r] + pb1);
    proj16[g1 + c0 + ln31]      = f2bf(acc10[r] + pb0);
    proj16[g1 + c0 + 32 + ln31] = f2bf(acc11[r] + pb1);
  }
}

// ---------------- stage 2: conv-as-3-shift-GEMM -> rep16 (16384x768x256) ---------
// block: 64 rows x 256 cols (grid 256). B register-direct from swizzled wtB.
__global__ __launch_bounds__(256) void k_conv_mfma(const unsigned short* __restrict__ proj16,
                                                   const unsigned short* __restrict__ wtB,
                                                   const float* __restrict__ cb,
                                                   const int* __restrict__ seq,
                                                   unsigned short* __restrict__ rep16) {
  __shared__ unsigned short As[32 * 66 * 8];  // (kk2*66 + row)*8, 33 KiB
  const int m0 = blockIdx.x * 64;
  const int bb = m0 >> 9, s0 = m0 & 511;
  const int t = threadIdx.x;
  const int w = t >> 6, lane = t & 63, ln31 = lane & 31, kh = lane >> 5;
  const int c0 = w * 64;

#pragma unroll
  for (int i = 0; i < 9; i++) {
    int c = t + i * 256;
    if (c < 2112) {
      int row = c >> 5, kk2 = c & 31;
      us8 v = {0, 0, 0, 0, 0, 0, 0, 0};
      if (s0 + row <= 511)
        v = *(const us8*)(proj16 + (size_t)(bb * S_ + s0 + row) * P_ + kk2 * 8);
      *(us8*)&As[(kk2 * 66 + row) * 8] = v;
    }
  }
  __syncthreads();

  f32x16 acc00, acc01, acc10, acc11;
#pragma unroll
  for (int r = 0; r < 16; r++) { acc00[r] = 0.f; acc01[r] = 0.f; acc10[r] = 0.f; acc11[r] = 0.f; }

  // ogrp = 2w and 2w+1; NK=48
  const unsigned short* bb0 = wtB + (size_t)(2 * w) * 48 * 512 + lane * 8;
  const unsigned short* bb1 = bb0 + (size_t)48 * 512;

#pragma unroll
  for (int k = 0; k < 3; k++) {
#pragma unroll
    for (int kk = 0; kk < 16; kk++) {
      bf16x8 a0 = *(const bf16x8*)&As[((2 * kk + kh) * 66 + k + ln31) * 8];
      bf16x8 a1 = *(const bf16x8*)&As[((2 * kk + kh) * 66 + k + 32 + ln31) * 8];
      bf16x8 b0 = *(const bf16x8*)(bb0 + (size_t)(k * 16 + kk) * 512);
      bf16x8 b1 = *(const bf16x8*)(bb1 + (size_t)(k * 16 + kk) * 512);
      acc00 = __builtin_amdgcn_mfma_f32_32x32x16_bf16(a0, b0, acc00, 0, 0, 0);
      acc01 = __builtin_amdgcn_mfma_f32_32x32x16_bf16(a0, b1, acc01, 0, 0, 0);
      acc10 = __builtin_amdgcn_mfma_f32_32x32x16_bf16(a1, b0, acc10, 0, 0, 0);
      acc11 = __builtin_amdgcn_mfma_f32_32x32x16_bf16(a1, b1, acc11, 0, 0, 0);
    }
  }

  int l = seq[bb];
  float cb0 = cb[c0 + ln31], cb1 = cb[c0 + 32 + ln31];
#pragma unroll
  for (int r = 0; r < 16; r++) {
    int rl = (r & 3) + 8 * (r >> 2) + 4 * kh;
    int s_a = s0 + rl, s_b = s0 + 32 + rl;
    float ma = (s_a >= 1 && s_a <= 509 && s_a < l - 1) ? 1.f : 0.f;
    float mb = (s_b >= 1 && s_b <= 509 && s_b < l - 1) ? 1.f : 0.f;
    size_t g0 = (size_t)(m0 + rl) * P_;
    size_t g1 = (size_t)(m0 + 32 + rl) * P_;
    rep16[g0 + c0 + ln31]      = f2bf(fmaxf(acc00[r] + cb0, 0.f) * ma);
    rep16[g0 + c0 + 32 + ln31] = f2bf(fmaxf(acc01[r] + cb1, 0.f) * ma);
    rep16[g1 + c0 + ln31]      = f2bf(fmaxf(acc10[r] + cb0, 0.f) * mb);
    rep16[g1 + c0 + 32 + ln31] = f2bf(fmaxf(acc11[r] + cb1, 0.f) * mb);
  }
}

// ---------------- stage 3: MFMA logits + exp + h-fold + Z-fold -> E16 bf16 -------
// block: 64 rows x 128 q (grid 256x4). 4 waves, each 64 rows x 32 q.
// ZERO LDS / ZERO barriers: A-fragments register-resident (32 x bf16x8 from
// fragment-native repF, coalesced 1 KB loads); B register-direct from awB.
__global__ __launch_bounds__(256, 2) void k_attn_mfma(const unsigned short* __restrict__ repF,
                                                      const unsigned short* __restrict__ awB,
                                                      const float* __restrict__ ab,
                                                      unsigned short* __restrict__ E16,
                                                      float* __restrict__ Z) {
  const int m0 = blockIdx.x * 64;
  const int q0 = blockIdx.y * 128;
  const int t = threadIdx.x;
  const int w = t >> 6;
  const int lane = t & 63;
  const int ln31 = lane & 31;
  const int kh = lane >> 5;

  // A-fragments: rows m0..m0+31 (ar0) and m0+32..m0+63 (ar1), all 16 kc blocks
  bf16x8 ar0[16], ar1[16];
  {
    const unsigned short* abase = repF + ((size_t)(m0 >> 5) * 16) * 512 + lane * 8;
#pragma unroll
    for (int kc = 0; kc < 16; kc++) {
      ar0[kc] = *(const bf16x8*)(abase + (size_t)kc * 512);
      ar1[kc] = *(const bf16x8*)(abase + (size_t)(16 + kc) * 512);
    }
  }

  const int qgidx = (q0 >> 5) + w;         // q-group 0..15
  const int qcol = qgidx * 32 + ln31;

  float ef0[16], ef1[16];
#pragma unroll
  for (int r = 0; r < 16; r++) { ef0[r] = 0.f; ef1[r] = 0.f; }

#pragma unroll 1
  for (int h = 0; h < HH; h++) {
    const unsigned short* bh = awB + ((size_t)(h * 16 + qgidx) * 16) * 512 + lane * 8;
    f32x16 acc0, acc1;
#pragma unroll
    for (int r = 0; r < 16; r++) { acc0[r] = 0.f; acc1[r] = 0.f; }

#pragma unroll
    for (int kc = 0; kc < 16; kc++) {
      bf16x8 b = *(const bf16x8*)(bh + (size_t)kc * 512);
      acc0 = __builtin_amdgcn_mfma_f32_32x32x16_bf16(ar0[kc], b, acc0, 0, 0, 0);
      acc1 = __builtin_amdgcn_mfma_f32_32x32x16_bf16(ar1[kc], b, acc1, 0, 0, 0);
    }
    float bias = ab[h * 512 + qcol];
#pragma unroll
    for (int r = 0; r < 16; r++) {
      ef0[r] += __expf(acc0[r] + bias);
      ef1[r] += __expf(acc1[r] + bias);
    }
  }

  // store E16 (bf16)
#pragma unroll
  for (int r = 0; r < 16; r++) {
    int rl = (r & 3) + 8 * (r >> 2) + 4 * kh;
    E16[(size_t)(m0 + rl) * 512 + qcol]      = f2bf(ef0[r]);
    E16[(size_t)(m0 + 32 + rl) * 512 + qcol] = f2bf(ef1[r]);
  }

  // Z partial row-sums: butterfly over the 32 q-lanes of each half-wave
#pragma unroll
  for (int r = 0; r < 16; r++) {
    float z0 = ef0[r];
    float z1 = ef1[r];
#pragma unroll
    for (int st = 16; st >= 1; st >>= 1) {
      z0 += __shfl_xor(z0, st, 64);
      z1 += __shfl_xor(z1, st, 64);
    }
    if (ln31 == 0) {
      int rl = (r & 3) + 8 * (r >> 2) + 4 * kh;
      atomicAdd(&Z[m0 + rl], z0);
      atomicAdd(&Z[m0 + 32 + rl], z1);
    }
  }
}

// ---------------- stage 4: w[b,q] = (1/H) sum_s E16[b,s,q]/Z[b,s] ----------------
__global__ __launch_bounds__(512) void k_w(const unsigned short* __restrict__ E16,
                                           const float* __restrict__ Z,
                                           float* __restrict__ wB) {
  __shared__ float rZ[64];
  int b = blockIdx.x, c = blockIdx.y, t = threadIdx.x;
  int s0 = c * 64;
  if (t < 64) rZ[t] = 1.0f / Z[b * 512 + s0 + t];
  __syncthreads();
  float acc = 0.f;
#pragma unroll 8
  for (int s = 0; s < 64; s++)
    acc += bf2f(E16[(size_t)(b * 512 + s0 + s) * 512 + t]) * rZ[s];
  atomicAdd(&wB[b * 512 + t], acc * (1.0f / HH));
}

// ---------------- stage 5a: repA[b,p] = sum_q w[b,q] * rep16[b,q,p] --------------
__global__ __launch_bounds__(256) void k_final_a(const unsigned short* __restrict__ rep16,
                                                 const float* __restrict__ wB,
                                                 float* __restrict__ repA) {
  __shared__ float wS[64];
  int b = blockIdx.x, qc = blockIdx.y, t = threadIdx.x;
  if (t < 64) wS[t] = wB[b * 512 + qc * 64 + t];
  __syncthreads();
  float acc = 0.f;
  const unsigned short* base = rep16 + (size_t)(b * 512 + qc * 64) * 256 + t;
#pragma unroll 8
  for (int q = 0; q < 64; q++) acc += wS[q] * bf2f(base[(size_t)q * 256]);
  atomicAdd(&repA[b * 256 + t], acc);
}

// ---------------- stage 5b: heads -> probs + argmax ------------------------------
__global__ __launch_bounds__(128) void k_final_b(const float* __restrict__ repA,
                                                 const float* __restrict__ c1w,
                                                 const float* __restrict__ c1b,
                                                 const float* __restrict__ c2w,
                                                 const float* __restrict__ c2b,
                                                 float* __restrict__ out) {
  __shared__ float hS[128];
  __shared__ float clsS[2];
  int b = blockIdx.x, t = threadIdx.x;
  float acc = c1b[t];
  for (int p = 0; p < 256; p++) acc += repA[b * 256 + p] * c1w[p * 128 + t];
  hS[t] = acc > 0.f ? acc : 0.01f * acc;
  __syncthreads();
  if (t < 2) {
    float a2 = c2b[t];
    for (int j = 0; j < 128; j++) a2 += hS[j] * c2w[j * 2 + t];
    clsS[t] = a2;
  }
  __syncthreads();
  if (t == 0) {
    float c0 = clsS[0], c1 = clsS[1];
    float m = fmaxf(c0, c1);
    float e0 = __expf(c0 - m), e1 = __expf(c1 - m);
    float inv = 1.0f / (e0 + e1);
    float p0 = e0 * inv, p1 = e1 * inv;
    out[b * 2 + 0] = p0;
    out[b * 2 + 1] = p1;
    out[B_ * 2 + b] = (p1 > p0) ? 1.0f : 0.0f;
  }
}

extern "C" void kernel_launch(void* const* d_in, const int* in_sizes, int n_in,
                              void* d_out, int out_size, void* d_ws, size_t ws_size,
                              hipStream_t stream) {
  const float* x   = (const float*)d_in[0];
  const int*   seq = (const int*)d_in[1];
  const float* pw  = (const float*)d_in[2];
  const float* pb  = (const float*)d_in[3];
  const float* cw  = (const float*)d_in[4];
  const float* cb  = (const float*)d_in[5];
  const float* aw  = (const float*)d_in[6];
  const float* ab  = (const float*)d_in[7];
  const float* c1w = (const float*)d_in[8];
  const float* c1b = (const float*)d_in[9];
  const float* c2w = (const float*)d_in[10];
  const float* c2b = (const float*)d_in[11];
  float* out = (float*)d_out;

  char* ws = (char*)d_ws;
  // proj16 (8 MiB) overlaps E16 (16 MiB): proj16 dies (k_conv) before E16 written
  unsigned short* proj16 = (unsigned short*)(ws);
  unsigned short* E16    = (unsigned short*)(ws);                     // 16 MiB @ 0
  unsigned short* rep16  = (unsigned short*)(ws + (size_t)16777216);  // 8 MiB
  unsigned short* pwT    = (unsigned short*)(ws + (size_t)25165824);  // 512 KiB
  unsigned short* wtT    = (unsigned short*)(ws + (size_t)25690112);  // 384 KiB
  unsigned short* awT    = (unsigned short*)(ws + (size_t)26083328);  // 2 MiB
  float*          Z      = (float*)(ws + (size_t)28180480);           // 64 KiB
  float*          wB     = (float*)(ws + (size_t)28246016);           // 64 KiB
  float*          repA   = (float*)(ws + (size_t)28311552);           // 32 KiB
  unsigned short* awB    = (unsigned short*)(ws + (size_t)28377088);  // 2 MiB swizzled
  unsigned short* pwB    = (unsigned short*)(ws + (size_t)30474240);  // 512 KiB swizzled
  unsigned short* wtB    = (unsigned short*)(ws + (size_t)30998528);  // 384 KiB swizzled
  unsigned short* repF   = (unsigned short*)(ws + (size_t)31391744);  // 8 MiB swizzled A

  k_zero<<<160, 256, 0, stream>>>(Z);  // Z + wB + repA contiguous (40960 floats)
  k_wtT<<<dim3(256, 3), 256, 0, stream>>>(cw, wtT);
  k_pwT<<<dim3(8, 32), 256, 0, stream>>>(pw, pwT);
  k_awT<<<dim3(128, 8), 256, 0, stream>>>(aw, awT);
  // fragment-native repack: grp count x NK/4
  k_swz<<<dim3(128, 4), 256, 0, stream>>>(awT, awB, 256, 16);
  k_swz<<<dim3(8, 16), 256, 0, stream>>>(pwT, pwB, 1024, 64);
  k_swz<<<dim3(8, 12), 256, 0, stream>>>(wtT, wtB, 768, 48);

  k_proj_mfma<<<256, 256, 0, stream>>>(x, pwB, pb, proj16);
  k_conv_mfma<<<256, 256, 0, stream>>>(proj16, wtB, cb, seq, rep16);
  k_swz<<<dim3(512, 4), 256, 0, stream>>>(rep16, repF, 256, 16);  // A-frags for attn
  k_attn_mfma<<<dim3(256, 4), 256, 0, stream>>>(repF, awB, ab, E16, Z);
  k_w<<<dim3(32, 8), 512, 0, stream>>>(E16, Z, wB);
  k_final_a<<<dim3(32, 8), 256, 0, stream>>>(rep16, wB, repA);
  k_final_b<<<32, 128, 0, stream>>>(repA, c1w, c1b, c2w, c2b, out);
}

// Round 9
// 237.405 us; speedup vs baseline: 1.5582x; 1.0511x over previous
//
#include <hip/hip_runtime.h>

#define B_ 32
#define S_ 512
#define E_ 1024
#define P_ 256
#define HH 8
// rows = B*S = 16384

typedef __attribute__((ext_vector_type(8))) short bf16x8;
typedef __attribute__((ext_vector_type(8))) unsigned short us8;
typedef __attribute__((ext_vector_type(4))) unsigned short us4;
typedef __attribute__((ext_vector_type(16))) float f32x16;
typedef __attribute__((ext_vector_type(4))) float f32x4;

static __device__ __forceinline__ unsigned short f2bf(float f) {
  union { float f; unsigned int u; } v;
  v.f = f;
  unsigned int r = (v.u + 0x7FFFu + ((v.u >> 16) & 1u)) >> 16;
  return (unsigned short)r;
}
static __device__ __forceinline__ float bf2f(unsigned short u) {
  union { unsigned int u; float f; } v;
  v.u = ((unsigned int)u) << 16;
  return v.f;
}

// ---------------- prep A: pw [k][n] fp32 -> pwB 32x32-frag-native bf16 -----------
// block (g, kc): lane holds pw[kc*16 + (l>>5)*8 + j][g*32 + (l&31)]
__global__ __launch_bounds__(256) void k_pwB(const float* __restrict__ pw,
                                             unsigned short* __restrict__ dst) {
  int g = blockIdx.x, kc = blockIdx.y * 4 + (threadIdx.x >> 6);
  int l = threadIdx.x & 63;
  int n = g * 32 + (l & 31);
  int kbase = kc * 16 + (l >> 5) * 8;
  us8 v;
#pragma unroll
  for (int j = 0; j < 8; j++) v[j] = f2bf(pw[(size_t)(kbase + j) * P_ + n]);
  *(us8*)(dst + ((size_t)g * 64 + kc) * 512 + l * 8) = v;
}

// ---------------- prep B: conv_w (O,I,K) fp32 -> wtB 32x32-frag-native bf16 ------
// virtual wtT[o][x=k*256+i]; block (g, kidx): lane holds wtT[g*32+(l&31)][kidx*16+(l>>5)*8+j]
__global__ __launch_bounds__(256) void k_wtB(const float* __restrict__ cw,
                                             unsigned short* __restrict__ dst) {
  int g = blockIdx.x, kidx = blockIdx.y * 4 + (threadIdx.x >> 6);
  int l = threadIdx.x & 63;
  int o = g * 32 + (l & 31);
  int xb = kidx * 16 + (l >> 5) * 8;
  us8 v;
#pragma unroll
  for (int j = 0; j < 8; j++) {
    int x = xb + j;
    int k = x >> 8, i = x & 255;
    v[j] = f2bf(cw[(size_t)o * 768 + i * 3 + k]);
  }
  *(us8*)(dst + ((size_t)g * 48 + kidx) * 512 + l * 8) = v;
}

// ---------------- prep C: attn_w [k][j] fp32 -> awB 16x16-frag-native bf16 -------
// block (g, ks): lane holds aw[ks*32 + (l>>4)*8 + j][g*16 + (l&15)]
__global__ __launch_bounds__(256) void k_awB16(const float* __restrict__ aw,
                                               unsigned short* __restrict__ dst) {
  int g = blockIdx.x, ks = blockIdx.y * 4 + (threadIdx.x >> 6);
  int l = threadIdx.x & 63;
  int j0 = g * 16 + (l & 15);
  int kbase = ks * 32 + (l >> 4) * 8;
  us8 v;
#pragma unroll
  for (int j = 0; j < 8; j++) v[j] = f2bf(aw[(size_t)(kbase + j) * 4096 + j0]);
  *(us8*)(dst + ((size_t)g * 8 + ks) * 512 + l * 8) = v;
}

// ---------------- prep D: rep16 [m][k] bf16 -> repF 16x16-frag-native ------------
// block (g, ks): lane holds rep16[g*16 + (l&15)][ks*32 + (l>>4)*8 .. +8]
__global__ __launch_bounds__(256) void k_swz16(const unsigned short* __restrict__ src,
                                               unsigned short* __restrict__ dst) {
  int g = blockIdx.x, ks = blockIdx.y * 4 + (threadIdx.x >> 6);
  int l = threadIdx.x & 63;
  us8 v = *(const us8*)(src + (size_t)(g * 16 + (l & 15)) * 256 + ks * 32 + (l >> 4) * 8);
  *(us8*)(dst + ((size_t)g * 8 + ks) * 512 + l * 8) = v;
}

// ---------------- zero Z (16K) + wB (16K) + repA (8K) floats, contiguous ---------
__global__ __launch_bounds__(256) void k_zero(float* __restrict__ p) {
  p[blockIdx.x * 256 + threadIdx.x] = 0.f;
}

// ---------------- stage 1: proj16 = bf16(x @ pw + pb)  (16384x1024x256) ----------
// (unchanged R7/R8 structure — proven best)
__global__ __launch_bounds__(256) void k_proj_mfma(const float* __restrict__ x,
                                                   const unsigned short* __restrict__ pwB,
                                                   const float* __restrict__ pb,
                                                   unsigned short* __restrict__ proj16) {
  __shared__ unsigned short As[16 * 64 * 8];  // (kk2*64 + row)*8, 16 KiB
  const int m0 = blockIdx.x * 64;
  const int t = threadIdx.x;
  const int w = t >> 6, lane = t & 63, ln31 = lane & 31, kh = lane >> 5;
  const int c0 = w * 64;

  f32x16 acc00, acc01, acc10, acc11;
#pragma unroll
  for (int r = 0; r < 16; r++) { acc00[r] = 0.f; acc01[r] = 0.f; acc10[r] = 0.f; acc11[r] = 0.f; }

  const unsigned short* bp0 = pwB + (size_t)(2 * w) * 64 * 512 + lane * 8;
  const unsigned short* bp1 = bp0 + (size_t)64 * 512;

  for (int kc = 0; kc < E_; kc += 128) {
#pragma unroll
    for (int i = 0; i < 8; i++) {
      int c = t + i * 256;
      int row = c >> 5, pos = c & 31;
      float4 v = *(const float4*)(x + (size_t)(m0 + row) * E_ + kc + pos * 4);
      us4 h;
      h[0] = f2bf(v.x); h[1] = f2bf(v.y); h[2] = f2bf(v.z); h[3] = f2bf(v.w);
      *(us4*)&As[((pos >> 1) * 64 + row) * 8 + (pos & 1) * 4] = h;
    }
    __syncthreads();
    const int kcs = kc >> 4;
#pragma unroll
    for (int kk = 0; kk < 8; kk++) {
      bf16x8 a0 = *(const bf16x8*)&As[((2 * kk + kh) * 64 + ln31) * 8];
      bf16x8 a1 = *(const bf16x8*)&As[((2 * kk + kh) * 64 + 32 + ln31) * 8];
      bf16x8 b0 = *(const bf16x8*)(bp0 + (size_t)(kcs + kk) * 512);
      bf16x8 b1 = *(const bf16x8*)(bp1 + (size_t)(kcs + kk) * 512);
      acc00 = __builtin_amdgcn_mfma_f32_32x32x16_bf16(a0, b0, acc00, 0, 0, 0);
      acc01 = __builtin_amdgcn_mfma_f32_32x32x16_bf16(a0, b1, acc01, 0, 0, 0);
      acc10 = __builtin_amdgcn_mfma_f32_32x32x16_bf16(a1, b0, acc10, 0, 0, 0);
      acc11 = __builtin_amdgcn_mfma_f32_32x32x16_bf16(a1, b1, acc11, 0, 0, 0);
    }
    __syncthreads();
  }
  float pb0 = pb[c0 + ln31], pb1 = pb[c0 + 32 + ln31];
#pragma unroll
  for (int r = 0; r < 16; r++) {
    int rl = (r & 3) + 8 * (r >> 2) + 4 * kh;
    size_t g0 = (size_t)(m0 + rl) * P_;
    size_t g1 = (size_t)(m0 + 32 + rl) * P_;
    proj16[g0 + c0 + ln31]      = f2bf(acc00[r] + pb0);
    proj16[g0 + c0 + 32 + ln31] = f2bf(acc01[r] + pb1);
    proj16[g1 + c0 + ln31]      = f2bf(acc10[r] + pb0);
    proj16[g1 + c0 + 32 + ln31] = f2bf(acc11[r] + pb1);
  }
}

// ---------------- stage 2: conv-as-3-shift-GEMM -> rep16 (16384x768x256) ---------
// (unchanged R7/R8 structure)
__global__ __launch_bounds__(256) void k_conv_mfma(const unsigned short* __restrict__ proj16,
                                                   const unsigned short* __restrict__ wtB,
                                                   const float* __restrict__ cb,
                                                   const int* __restrict__ seq,
                                                   unsigned short* __restrict__ rep16) {
  __shared__ unsigned short As[32 * 66 * 8];  // (kk2*66 + row)*8, 33 KiB
  const int m0 = blockIdx.x * 64;
  const int bb = m0 >> 9, s0 = m0 & 511;
  const int t = threadIdx.x;
  const int w = t >> 6, lane = t & 63, ln31 = lane & 31, kh = lane >> 5;
  const int c0 = w * 64;

#pragma unroll
  for (int i = 0; i < 9; i++) {
    int c = t + i * 256;
    if (c < 2112) {
      int row = c >> 5, kk2 = c & 31;
      us8 v = {0, 0, 0, 0, 0, 0, 0, 0};
      if (s0 + row <= 511)
        v = *(const us8*)(proj16 + (size_t)(bb * S_ + s0 + row) * P_ + kk2 * 8);
      *(us8*)&As[(kk2 * 66 + row) * 8] = v;
    }
  }
  __syncthreads();

  f32x16 acc00, acc01, acc10, acc11;
#pragma unroll
  for (int r = 0; r < 16; r++) { acc00[r] = 0.f; acc01[r] = 0.f; acc10[r] = 0.f; acc11[r] = 0.f; }

  const unsigned short* bb0 = wtB + (size_t)(2 * w) * 48 * 512 + lane * 8;
  const unsigned short* bb1 = bb0 + (size_t)48 * 512;

#pragma unroll
  for (int k = 0; k < 3; k++) {
#pragma unroll
    for (int kk = 0; kk < 16; kk++) {
      bf16x8 a0 = *(const bf16x8*)&As[((2 * kk + kh) * 66 + k + ln31) * 8];
      bf16x8 a1 = *(const bf16x8*)&As[((2 * kk + kh) * 66 + k + 32 + ln31) * 8];
      bf16x8 b0 = *(const bf16x8*)(bb0 + (size_t)(k * 16 + kk) * 512);
      bf16x8 b1 = *(const bf16x8*)(bb1 + (size_t)(k * 16 + kk) * 512);
      acc00 = __builtin_amdgcn_mfma_f32_32x32x16_bf16(a0, b0, acc00, 0, 0, 0);
      acc01 = __builtin_amdgcn_mfma_f32_32x32x16_bf16(a0, b1, acc01, 0, 0, 0);
      acc10 = __builtin_amdgcn_mfma_f32_32x32x16_bf16(a1, b0, acc10, 0, 0, 0);
      acc11 = __builtin_amdgcn_mfma_f32_32x32x16_bf16(a1, b1, acc11, 0, 0, 0);
    }
  }

  int l = seq[bb];
  float cb0 = cb[c0 + ln31], cb1 = cb[c0 + 32 + ln31];
#pragma unroll
  for (int r = 0; r < 16; r++) {
    int rl = (r & 3) + 8 * (r >> 2) + 4 * kh;
    int s_a = s0 + rl, s_b = s0 + 32 + rl;
    float ma = (s_a >= 1 && s_a <= 509 && s_a < l - 1) ? 1.f : 0.f;
    float mb = (s_b >= 1 && s_b <= 509 && s_b < l - 1) ? 1.f : 0.f;
    size_t g0 = (size_t)(m0 + rl) * P_;
    size_t g1 = (size_t)(m0 + 32 + rl) * P_;
    rep16[g0 + c0 + ln31]      = f2bf(fmaxf(acc00[r] + cb0, 0.f) * ma);
    rep16[g0 + c0 + 32 + ln31] = f2bf(fmaxf(acc01[r] + cb1, 0.f) * ma);
    rep16[g1 + c0 + ln31]      = f2bf(fmaxf(acc10[r] + cb0, 0.f) * mb);
    rep16[g1 + c0 + 32 + ln31] = f2bf(fmaxf(acc11[r] + cb1, 0.f) * mb);
  }
}

// ---------------- stage 3: 16x16x32 MFMA logits + exp + h-fold + Z -> E16 --------
// block: 64 rows x 128 q (grid 256x4). Wave: 64 rows x 32 q as 4 row-tiles x
// 2 q-tiles = 8 INDEPENDENT MFMA chains (depth 8). Zero LDS, zero barriers.
// A frags register-resident from repF; B register-direct from awB (coalesced 1KB).
__global__ __launch_bounds__(256, 2) void k_attn_mfma(const unsigned short* __restrict__ repF,
                                                      const unsigned short* __restrict__ awB,
                                                      const float* __restrict__ ab,
                                                      unsigned short* __restrict__ E16,
                                                      float* __restrict__ Z) {
  const int m0 = blockIdx.x * 64;
  const int q0 = blockIdx.y * 128;
  const int t = threadIdx.x;
  const int w = t >> 6, lane = t & 63;
  const int ln15 = lane & 15, l4 = lane >> 4;

  // A-fragments: 4 row-tiles x 8 k-steps, 128 VGPR total
  bf16x8 ar[4][8];
  {
    const unsigned short* abase = repF + (size_t)(m0 >> 4) * 8 * 512 + lane * 8;
#pragma unroll
    for (int rt = 0; rt < 4; rt++)
#pragma unroll
      for (int ks = 0; ks < 8; ks++)
        ar[rt][ks] = *(const bf16x8*)(abase + (size_t)(rt * 8 + ks) * 512);
  }

  const int qg = (q0 >> 5) + w;  // q-group 0..15 (32 q each)

  f32x4 ef[8];
#pragma unroll
  for (int i = 0; i < 8; i++) ef[i] = (f32x4){0.f, 0.f, 0.f, 0.f};

#pragma unroll 1
  for (int h = 0; h < HH; h++) {
    const unsigned short* bh = awB + (size_t)(h * 32 + qg * 2) * 8 * 512 + lane * 8;
    f32x4 acc[8];
#pragma unroll
    for (int i = 0; i < 8; i++) acc[i] = (f32x4){0.f, 0.f, 0.f, 0.f};
#pragma unroll
    for (int ks = 0; ks < 8; ks++) {
      bf16x8 b0 = *(const bf16x8*)(bh + (size_t)ks * 512);
      bf16x8 b1 = *(const bf16x8*)(bh + (size_t)(8 + ks) * 512);
#pragma unroll
      for (int rt = 0; rt < 4; rt++) {
        acc[rt * 2 + 0] = __builtin_amdgcn_mfma_f32_16x16x32_bf16(ar[rt][ks], b0, acc[rt * 2 + 0], 0, 0, 0);
        acc[rt * 2 + 1] = __builtin_amdgcn_mfma_f32_16x16x32_bf16(ar[rt][ks], b1, acc[rt * 2 + 1], 0, 0, 0);
      }
    }
    float bias0 = ab[h * 512 + qg * 32 + ln15];
    float bias1 = ab[h * 512 + qg * 32 + 16 + ln15];
#pragma unroll
    for (int rt = 0; rt < 4; rt++)
#pragma unroll
      for (int r = 0; r < 4; r++) {
        ef[rt * 2 + 0][r] += __expf(acc[rt * 2 + 0][r] + bias0);
        ef[rt * 2 + 1][r] += __expf(acc[rt * 2 + 1][r] + bias1);
      }
  }

  // store E16: row = m0 + rt*16 + l4*4 + r; cols qg*32 + {ln15, 16+ln15}
#pragma unroll
  for (int rt = 0; rt < 4; rt++)
#pragma unroll
    for (int r = 0; r < 4; r++) {
      int row = m0 + rt * 16 + l4 * 4 + r;
      E16[(size_t)row * 512 + qg * 32 + ln15]      = f2bf(ef[rt * 2 + 0][r]);
      E16[(size_t)row * 512 + qg * 32 + 16 + ln15] = f2bf(ef[rt * 2 + 1][r]);
    }

  // Z partial row-sums: butterfly over the 16 q-lanes of each quarter-wave
#pragma unroll
  for (int rt = 0; rt < 4; rt++)
#pragma unroll
    for (int r = 0; r < 4; r++) {
      float z = ef[rt * 2 + 0][r] + ef[rt * 2 + 1][r];
#pragma unroll
      for (int st = 8; st >= 1; st >>= 1) z += __shfl_xor(z, st, 64);
      if (ln15 == 0) atomicAdd(&Z[m0 + rt * 16 + l4 * 4 + r], z);
    }
}

// ---------------- stage 4: w[b,q] = (1/H) sum_s E16[b,s,q]/Z[b,s] ----------------
__global__ __launch_bounds__(512) void k_w(const unsigned short* __restrict__ E16,
                                           const float* __restrict__ Z,
                                           float* __restrict__ wB) {
  __shared__ float rZ[64];
  int b = blockIdx.x, c = blockIdx.y, t = threadIdx.x;
  int s0 = c * 64;
  if (t < 64) rZ[t] = 1.0f / Z[b * 512 + s0 + t];
  __syncthreads();
  float acc = 0.f;
#pragma unroll 8
  for (int s = 0; s < 64; s++)
    acc += bf2f(E16[(size_t)(b * 512 + s0 + s) * 512 + t]) * rZ[s];
  atomicAdd(&wB[b * 512 + t], acc * (1.0f / HH));
}

// ---------------- stage 5a: repA[b,p] = sum_q w[b,q] * rep16[b,q,p] --------------
__global__ __launch_bounds__(256) void k_final_a(const unsigned short* __restrict__ rep16,
                                                 const float* __restrict__ wB,
                                                 float* __restrict__ repA) {
  __shared__ float wS[64];
  int b = blockIdx.x, qc = blockIdx.y, t = threadIdx.x;
  if (t < 64) wS[t] = wB[b * 512 + qc * 64 + t];
  __syncthreads();
  float acc = 0.f;
  const unsigned short* base = rep16 + (size_t)(b * 512 + qc * 64) * 256 + t;
#pragma unroll 8
  for (int q = 0; q < 64; q++) acc += wS[q] * bf2f(base[(size_t)q * 256]);
  atomicAdd(&repA[b * 256 + t], acc);
}

// ---------------- stage 5b: heads -> probs + argmax ------------------------------
__global__ __launch_bounds__(128) void k_final_b(const float* __restrict__ repA,
                                                 const float* __restrict__ c1w,
                                                 const float* __restrict__ c1b,
                                                 const float* __restrict__ c2w,
                                                 const float* __restrict__ c2b,
                                                 float* __restrict__ out) {
  __shared__ float hS[128];
  __shared__ float clsS[2];
  int b = blockIdx.x, t = threadIdx.x;
  float acc = c1b[t];
  for (int p = 0; p < 256; p++) acc += repA[b * 256 + p] * c1w[p * 128 + t];
  hS[t] = acc > 0.f ? acc : 0.01f * acc;
  __syncthreads();
  if (t < 2) {
    float a2 = c2b[t];
    for (int j = 0; j < 128; j++) a2 += hS[j] * c2w[j * 2 + t];
    clsS[t] = a2;
  }
  __syncthreads();
  if (t == 0) {
    float c0 = clsS[0], c1 = clsS[1];
    float m = fmaxf(c0, c1);
    float e0 = __expf(c0 - m), e1 = __expf(c1 - m);
    float inv = 1.0f / (e0 + e1);
    float p0 = e0 * inv, p1 = e1 * inv;
    out[b * 2 + 0] = p0;
    out[b * 2 + 1] = p1;
    out[B_ * 2 + b] = (p1 > p0) ? 1.0f : 0.0f;
  }
}

extern "C" void kernel_launch(void* const* d_in, const int* in_sizes, int n_in,
                              void* d_out, int out_size, void* d_ws, size_t ws_size,
                              hipStream_t stream) {
  const float* x   = (const float*)d_in[0];
  const int*   seq = (const int*)d_in[1];
  const float* pw  = (const float*)d_in[2];
  const float* pb  = (const float*)d_in[3];
  const float* cw  = (const float*)d_in[4];
  const float* cb  = (const float*)d_in[5];
  const float* aw  = (const float*)d_in[6];
  const float* ab  = (const float*)d_in[7];
  const float* c1w = (const float*)d_in[8];
  const float* c1b = (const float*)d_in[9];
  const float* c2w = (const float*)d_in[10];
  const float* c2b = (const float*)d_in[11];
  float* out = (float*)d_out;

  char* ws = (char*)d_ws;
  // proj16 (8 MiB) aliases E16 (16 MiB): proj16 dies (k_conv) before E16 written
  unsigned short* proj16 = (unsigned short*)(ws);
  unsigned short* E16    = (unsigned short*)(ws);                     // 16 MiB @ 0
  unsigned short* rep16  = (unsigned short*)(ws + (size_t)16777216);  // 8 MiB
  unsigned short* repF   = (unsigned short*)(ws + (size_t)25165824);  // 8 MiB
  unsigned short* awB    = (unsigned short*)(ws + (size_t)33554432);  // 2 MiB
  unsigned short* pwB    = (unsigned short*)(ws + (size_t)35651584);  // 512 KiB
  unsigned short* wtB    = (unsigned short*)(ws + (size_t)36175872);  // 384 KiB
  float*          Z      = (float*)(ws + (size_t)36569088);           // 64 KiB
  float*          wB     = (float*)(ws + (size_t)36634624);           // 64 KiB
  float*          repA   = (float*)(ws + (size_t)36700160);           // 32 KiB

  k_zero<<<160, 256, 0, stream>>>(Z);  // Z + wB + repA contiguous (40960 floats)
  k_pwB<<<dim3(8, 16), 256, 0, stream>>>(pw, pwB);
  k_wtB<<<dim3(8, 12), 256, 0, stream>>>(cw, wtB);
  k_awB16<<<dim3(256, 2), 256, 0, stream>>>(aw, awB);

  k_proj_mfma<<<256, 256, 0, stream>>>(x, pwB, pb, proj16);
  k_conv_mfma<<<256, 256, 0, stream>>>(proj16, wtB, cb, seq, rep16);
  k_swz16<<<dim3(1024, 2), 256, 0, stream>>>(rep16, repF);
  k_attn_mfma<<<dim3(256, 4), 256, 0, stream>>>(repF, awB, ab, E16, Z);
  k_w<<<dim3(32, 8), 512, 0, stream>>>(E16, Z, wB);
  k_final_a<<<dim3(32, 8), 256, 0, stream>>>(rep16, wB, repA);
  k_final_b<<<32, 128, 0, stream>>>(repA, c1w, c1b, c2w, c2b, out);
}

// Round 10
// 225.057 us; speedup vs baseline: 1.6437x; 1.0549x over previous
//
#include <hip/hip_runtime.h>
#include <hip/hip_fp8.h>

#define B_ 32
#define S_ 512
#define E_ 1024
#define P_ 256
#define HH 8
// rows = B*S = 16384

typedef __attribute__((ext_vector_type(8))) short bf16x8;
typedef __attribute__((ext_vector_type(8))) unsigned short us8;
typedef __attribute__((ext_vector_type(4))) unsigned short us4;
typedef __attribute__((ext_vector_type(16))) float f32x16;
typedef __attribute__((ext_vector_type(4))) float f32x4;
typedef __attribute__((ext_vector_type(8))) unsigned char u8x8;

#define SA 8.0f
#define SB 16.0f
#define SINV (1.0f / 128.0f)

static __device__ __forceinline__ unsigned short f2bf(float f) {
  union { float f; unsigned int u; } v;
  v.f = f;
  unsigned int r = (v.u + 0x7FFFu + ((v.u >> 16) & 1u)) >> 16;
  return (unsigned short)r;
}
static __device__ __forceinline__ float bf2f(unsigned short u) {
  union { unsigned int u; float f; } v;
  v.u = ((unsigned int)u) << 16;
  return v.f;
}
static __device__ __forceinline__ unsigned char f2fp8(float f) {
  return (unsigned char)__hip_cvt_float_to_fp8(f, __HIP_SATFINITE, __HIP_E4M3);
}

// ---------------- prep A: pw [k][n] fp32 -> pwB 32x32-frag-native bf16 -----------
__global__ __launch_bounds__(256) void k_pwB(const float* __restrict__ pw,
                                             unsigned short* __restrict__ dst) {
  int g = blockIdx.x, kc = blockIdx.y * 4 + (threadIdx.x >> 6);
  int l = threadIdx.x & 63;
  int n = g * 32 + (l & 31);
  int kbase = kc * 16 + (l >> 5) * 8;
  us8 v;
#pragma unroll
  for (int j = 0; j < 8; j++) v[j] = f2bf(pw[(size_t)(kbase + j) * P_ + n]);
  *(us8*)(dst + ((size_t)g * 64 + kc) * 512 + l * 8) = v;
}

// ---------------- prep B: conv_w (O,I,K) fp32 -> wtB 32x32-frag-native bf16 ------
__global__ __launch_bounds__(256) void k_wtB(const float* __restrict__ cw,
                                             unsigned short* __restrict__ dst) {
  int g = blockIdx.x, kidx = blockIdx.y * 4 + (threadIdx.x >> 6);
  int l = threadIdx.x & 63;
  int o = g * 32 + (l & 31);
  int xb = kidx * 16 + (l >> 5) * 8;
  us8 v;
#pragma unroll
  for (int j = 0; j < 8; j++) {
    int x = xb + j;
    int k = x >> 8, i = x & 255;
    v[j] = f2bf(cw[(size_t)o * 768 + i * 3 + k]);
  }
  *(us8*)(dst + ((size_t)g * 48 + kidx) * 512 + l * 8) = v;
}

// ---------------- prep C: attn_w [k][j] fp32 -> awB8 16x16x32-frag fp8 (xSB) -----
// block (g over 256 16-col groups of j, ks 0..7): lane l holds
// aw[ks*32 + (l>>4)*8 + j][g*16 + (l&15)] * SB as fp8; 512 B per (g,ks) block.
__global__ __launch_bounds__(256) void k_awB8(const float* __restrict__ aw,
                                              unsigned char* __restrict__ dst) {
  int g = blockIdx.x, ks = blockIdx.y * 4 + (threadIdx.x >> 6);
  int l = threadIdx.x & 63;
  int j0 = g * 16 + (l & 15);
  int kbase = ks * 32 + (l >> 4) * 8;
  u8x8 v;
#pragma unroll
  for (int j = 0; j < 8; j++) v[j] = f2fp8(aw[(size_t)(kbase + j) * 4096 + j0] * SB);
  *(u8x8*)(dst + ((size_t)g * 8 + ks) * 512 + l * 8) = v;
}

// ---------------- prep D: rep16 bf16 -> repF8 16x16x32-frag fp8 (xSA) ------------
__global__ __launch_bounds__(256) void k_swz8(const unsigned short* __restrict__ src,
                                              unsigned char* __restrict__ dst) {
  int g = blockIdx.x, ks = blockIdx.y * 4 + (threadIdx.x >> 6);
  int l = threadIdx.x & 63;
  us8 v = *(const us8*)(src + (size_t)(g * 16 + (l & 15)) * 256 + ks * 32 + (l >> 4) * 8);
  u8x8 o;
#pragma unroll
  for (int j = 0; j < 8; j++) o[j] = f2fp8(bf2f(v[j]) * SA);
  *(u8x8*)(dst + ((size_t)g * 8 + ks) * 512 + l * 8) = o;
}

// ---------------- zero Z (16K) + wB (16K) + repA (8K) floats, contiguous ---------
__global__ __launch_bounds__(256) void k_zero(float* __restrict__ p) {
  p[blockIdx.x * 256 + threadIdx.x] = 0.f;
}

// ---------------- stage 1: proj16 = bf16(x @ pw + pb)  (16384x1024x256) ----------
__global__ __launch_bounds__(256) void k_proj_mfma(const float* __restrict__ x,
                                                   const unsigned short* __restrict__ pwB,
                                                   const float* __restrict__ pb,
                                                   unsigned short* __restrict__ proj16) {
  __shared__ unsigned short As[16 * 64 * 8];  // (kk2*64 + row)*8, 16 KiB
  const int m0 = blockIdx.x * 64;
  const int t = threadIdx.x;
  const int w = t >> 6, lane = t & 63, ln31 = lane & 31, kh = lane >> 5;
  const int c0 = w * 64;

  f32x16 acc00, acc01, acc10, acc11;
#pragma unroll
  for (int r = 0; r < 16; r++) { acc00[r] = 0.f; acc01[r] = 0.f; acc10[r] = 0.f; acc11[r] = 0.f; }

  const unsigned short* bp0 = pwB + (size_t)(2 * w) * 64 * 512 + lane * 8;
  const unsigned short* bp1 = bp0 + (size_t)64 * 512;

  for (int kc = 0; kc < E_; kc += 128) {
#pragma unroll
    for (int i = 0; i < 8; i++) {
      int c = t + i * 256;
      int row = c >> 5, pos = c & 31;
      float4 v = *(const float4*)(x + (size_t)(m0 + row) * E_ + kc + pos * 4);
      us4 h;
      h[0] = f2bf(v.x); h[1] = f2bf(v.y); h[2] = f2bf(v.z); h[3] = f2bf(v.w);
      *(us4*)&As[((pos >> 1) * 64 + row) * 8 + (pos & 1) * 4] = h;
    }
    __syncthreads();
    const int kcs = kc >> 4;
#pragma unroll
    for (int kk = 0; kk < 8; kk++) {
      bf16x8 a0 = *(const bf16x8*)&As[((2 * kk + kh) * 64 + ln31) * 8];
      bf16x8 a1 = *(const bf16x8*)&As[((2 * kk + kh) * 64 + 32 + ln31) * 8];
      bf16x8 b0 = *(const bf16x8*)(bp0 + (size_t)(kcs + kk) * 512);
      bf16x8 b1 = *(const bf16x8*)(bp1 + (size_t)(kcs + kk) * 512);
      acc00 = __builtin_amdgcn_mfma_f32_32x32x16_bf16(a0, b0, acc00, 0, 0, 0);
      acc01 = __builtin_amdgcn_mfma_f32_32x32x16_bf16(a0, b1, acc01, 0, 0, 0);
      acc10 = __builtin_amdgcn_mfma_f32_32x32x16_bf16(a1, b0, acc10, 0, 0, 0);
      acc11 = __builtin_amdgcn_mfma_f32_32x32x16_bf16(a1, b1, acc11, 0, 0, 0);
    }
    __syncthreads();
  }
  float pb0 = pb[c0 + ln31], pb1 = pb[c0 + 32 + ln31];
#pragma unroll
  for (int r = 0; r < 16; r++) {
    int rl = (r & 3) + 8 * (r >> 2) + 4 * kh;
    size_t g0 = (size_t)(m0 + rl) * P_;
    size_t g1 = (size_t)(m0 + 32 + rl) * P_;
    proj16[g0 + c0 + ln31]      = f2bf(acc00[r] + pb0);
    proj16[g0 + c0 + 32 + ln31] = f2bf(acc01[r] + pb1);
    proj16[g1 + c0 + ln31]      = f2bf(acc10[r] + pb0);
    proj16[g1 + c0 + 32 + ln31] = f2bf(acc11[r] + pb1);
  }
}

// ---------------- stage 2: conv-as-3-shift-GEMM -> rep16 (16384x768x256) ---------
__global__ __launch_bounds__(256) void k_conv_mfma(const unsigned short* __restrict__ proj16,
                                                   const unsigned short* __restrict__ wtB,
                                                   const float* __restrict__ cb,
                                                   const int* __restrict__ seq,
                                                   unsigned short* __restrict__ rep16) {
  __shared__ unsigned short As[32 * 66 * 8];  // (kk2*66 + row)*8, 33 KiB
  const int m0 = blockIdx.x * 64;
  const int bb = m0 >> 9, s0 = m0 & 511;
  const int t = threadIdx.x;
  const int w = t >> 6, lane = t & 63, ln31 = lane & 31, kh = lane >> 5;
  const int c0 = w * 64;

#pragma unroll
  for (int i = 0; i < 9; i++) {
    int c = t + i * 256;
    if (c < 2112) {
      int row = c >> 5, kk2 = c & 31;
      us8 v = {0, 0, 0, 0, 0, 0, 0, 0};
      if (s0 + row <= 511)
        v = *(const us8*)(proj16 + (size_t)(bb * S_ + s0 + row) * P_ + kk2 * 8);
      *(us8*)&As[(kk2 * 66 + row) * 8] = v;
    }
  }
  __syncthreads();

  f32x16 acc00, acc01, acc10, acc11;
#pragma unroll
  for (int r = 0; r < 16; r++) { acc00[r] = 0.f; acc01[r] = 0.f; acc10[r] = 0.f; acc11[r] = 0.f; }

  const unsigned short* bb0 = wtB + (size_t)(2 * w) * 48 * 512 + lane * 8;
  const unsigned short* bb1 = bb0 + (size_t)48 * 512;

#pragma unroll
  for (int k = 0; k < 3; k++) {
#pragma unroll
    for (int kk = 0; kk < 16; kk++) {
      bf16x8 a0 = *(const bf16x8*)&As[((2 * kk + kh) * 66 + k + ln31) * 8];
      bf16x8 a1 = *(const bf16x8*)&As[((2 * kk + kh) * 66 + k + 32 + ln31) * 8];
      bf16x8 b0 = *(const bf16x8*)(bb0 + (size_t)(k * 16 + kk) * 512);
      bf16x8 b1 = *(const bf16x8*)(bb1 + (size_t)(k * 16 + kk) * 512);
      acc00 = __builtin_amdgcn_mfma_f32_32x32x16_bf16(a0, b0, acc00, 0, 0, 0);
      acc01 = __builtin_amdgcn_mfma_f32_32x32x16_bf16(a0, b1, acc01, 0, 0, 0);
      acc10 = __builtin_amdgcn_mfma_f32_32x32x16_bf16(a1, b0, acc10, 0, 0, 0);
      acc11 = __builtin_amdgcn_mfma_f32_32x32x16_bf16(a1, b1, acc11, 0, 0, 0);
    }
  }

  int l = seq[bb];
  float cb0 = cb[c0 + ln31], cb1 = cb[c0 + 32 + ln31];
#pragma unroll
  for (int r = 0; r < 16; r++) {
    int rl = (r & 3) + 8 * (r >> 2) + 4 * kh;
    int s_a = s0 + rl, s_b = s0 + 32 + rl;
    float ma = (s_a >= 1 && s_a <= 509 && s_a < l - 1) ? 1.f : 0.f;
    float mb = (s_b >= 1 && s_b <= 509 && s_b < l - 1) ? 1.f : 0.f;
    size_t g0 = (size_t)(m0 + rl) * P_;
    size_t g1 = (size_t)(m0 + 32 + rl) * P_;
    rep16[g0 + c0 + ln31]      = f2bf(fmaxf(acc00[r] + cb0, 0.f) * ma);
    rep16[g0 + c0 + 32 + ln31] = f2bf(fmaxf(acc01[r] + cb1, 0.f) * ma);
    rep16[g1 + c0 + ln31]      = f2bf(fmaxf(acc10[r] + cb0, 0.f) * mb);
    rep16[g1 + c0 + 32 + ln31] = f2bf(fmaxf(acc11[r] + cb1, 0.f) * mb);
  }
}

// ---------------- stage 3: fp8 16x16x32 MFMA logits + exp + h-fold + Z -> E16 ----
// block: 64 rows x 128 q (grid 256x4). Wave: 64 rows x 32 q = 8 independent
// chains (4 row-tiles x 2 q-tiles). A frags fp8 register-resident (64 VGPR);
// B fp8 register-direct (512 B coalesced per load). Zero LDS, zero barriers.
__global__ __launch_bounds__(256, 2) void k_attn_mfma(const unsigned char* __restrict__ repF8,
                                                      const unsigned char* __restrict__ awB8,
                                                      const float* __restrict__ ab,
                                                      unsigned short* __restrict__ E16,
                                                      float* __restrict__ Z) {
  const int m0 = blockIdx.x * 64;
  const int q0 = blockIdx.y * 128;
  const int t = threadIdx.x;
  const int w = t >> 6, lane = t & 63;
  const int ln15 = lane & 15, l4 = lane >> 4;

  // A-fragments: 4 row-tiles x 8 k-steps x 8 fp8 = 64 VGPR total
  long ar[4][8];
  {
    const unsigned char* abase = repF8 + (size_t)(m0 >> 4) * 8 * 512 + lane * 8;
#pragma unroll
    for (int rt = 0; rt < 4; rt++)
#pragma unroll
      for (int ks = 0; ks < 8; ks++)
        ar[rt][ks] = *(const long*)(abase + (size_t)(rt * 8 + ks) * 512);
  }

  const int qg = (q0 >> 5) + w;  // q-group 0..15 (32 q each)

  f32x4 ef[8];
#pragma unroll
  for (int i = 0; i < 8; i++) ef[i] = (f32x4){0.f, 0.f, 0.f, 0.f};

#pragma unroll 1
  for (int h = 0; h < HH; h++) {
    const unsigned char* bh = awB8 + (size_t)(h * 32 + qg * 2) * 8 * 512 + lane * 8;
    f32x4 acc[8];
#pragma unroll
    for (int i = 0; i < 8; i++) acc[i] = (f32x4){0.f, 0.f, 0.f, 0.f};
#pragma unroll
    for (int ks = 0; ks < 8; ks++) {
      long b0 = *(const long*)(bh + (size_t)ks * 512);
      long b1 = *(const long*)(bh + (size_t)(8 + ks) * 512);
#pragma unroll
      for (int rt = 0; rt < 4; rt++) {
        acc[rt * 2 + 0] = __builtin_amdgcn_mfma_f32_16x16x32_fp8_fp8(ar[rt][ks], b0, acc[rt * 2 + 0], 0, 0, 0);
        acc[rt * 2 + 1] = __builtin_amdgcn_mfma_f32_16x16x32_fp8_fp8(ar[rt][ks], b1, acc[rt * 2 + 1], 0, 0, 0);
      }
    }
    float bias0 = ab[h * 512 + qg * 32 + ln15];
    float bias1 = ab[h * 512 + qg * 32 + 16 + ln15];
#pragma unroll
    for (int rt = 0; rt < 4; rt++)
#pragma unroll
      for (int r = 0; r < 4; r++) {
        ef[rt * 2 + 0][r] += __expf(acc[rt * 2 + 0][r] * SINV + bias0);
        ef[rt * 2 + 1][r] += __expf(acc[rt * 2 + 1][r] * SINV + bias1);
      }
  }

  // store E16: row = m0 + rt*16 + l4*4 + r; cols qg*32 + {ln15, 16+ln15}
#pragma unroll
  for (int rt = 0; rt < 4; rt++)
#pragma unroll
    for (int r = 0; r < 4; r++) {
      int row = m0 + rt * 16 + l4 * 4 + r;
      E16[(size_t)row * 512 + qg * 32 + ln15]      = f2bf(ef[rt * 2 + 0][r]);
      E16[(size_t)row * 512 + qg * 32 + 16 + ln15] = f2bf(ef[rt * 2 + 1][r]);
    }

  // Z partial row-sums: butterfly over the 16 q-lanes of each quarter-wave
#pragma unroll
  for (int rt = 0; rt < 4; rt++)
#pragma unroll
    for (int r = 0; r < 4; r++) {
      float z = ef[rt * 2 + 0][r] + ef[rt * 2 + 1][r];
#pragma unroll
      for (int st = 8; st >= 1; st >>= 1) z += __shfl_xor(z, st, 64);
      if (ln15 == 0) atomicAdd(&Z[m0 + rt * 16 + l4 * 4 + r], z);
    }
}

// ---------------- stage 4: w[b,q] = (1/H) sum_s E16[b,s,q]/Z[b,s] ----------------
__global__ __launch_bounds__(512) void k_w(const unsigned short* __restrict__ E16,
                                           const float* __restrict__ Z,
                                           float* __restrict__ wB) {
  __shared__ float rZ[64];
  int b = blockIdx.x, c = blockIdx.y, t = threadIdx.x;
  int s0 = c * 64;
  if (t < 64) rZ[t] = 1.0f / Z[b * 512 + s0 + t];
  __syncthreads();
  float acc = 0.f;
#pragma unroll 8
  for (int s = 0; s < 64; s++)
    acc += bf2f(E16[(size_t)(b * 512 + s0 + s) * 512 + t]) * rZ[s];
  atomicAdd(&wB[b * 512 + t], acc * (1.0f / HH));
}

// ---------------- stage 5a: repA[b,p] = sum_q w[b,q] * rep16[b,q,p] --------------
// Coalesced: each wave reads whole 512 B rows (us4/lane); thread t covers
// p-quad (t&63)*4, q-offset t>>6 (4 rows in flight).
__global__ __launch_bounds__(256) void k_final_a(const unsigned short* __restrict__ rep16,
                                                 const float* __restrict__ wB,
                                                 float* __restrict__ repA) {
  __shared__ float wS[64];
  int b = blockIdx.x, qc = blockIdx.y, t = threadIdx.x;
  if (t < 64) wS[t] = wB[b * 512 + qc * 64 + t];
  __syncthreads();
  int p0 = (t & 63) * 4, qo = t >> 6;
  float a0 = 0.f, a1 = 0.f, a2 = 0.f, a3 = 0.f;
  for (int q = qo; q < 64; q += 4) {
    us4 v = *(const us4*)(rep16 + (size_t)(b * 512 + qc * 64 + q) * 256 + p0);
    float wq = wS[q];
    a0 += wq * bf2f(v[0]); a1 += wq * bf2f(v[1]);
    a2 += wq * bf2f(v[2]); a3 += wq * bf2f(v[3]);
  }
  atomicAdd(&repA[b * 256 + p0 + 0], a0);
  atomicAdd(&repA[b * 256 + p0 + 1], a1);
  atomicAdd(&repA[b * 256 + p0 + 2], a2);
  atomicAdd(&repA[b * 256 + p0 + 3], a3);
}

// ---------------- stage 5b: heads -> probs + argmax ------------------------------
__global__ __launch_bounds__(128) void k_final_b(const float* __restrict__ repA,
                                                 const float* __restrict__ c1w,
                                                 const float* __restrict__ c1b,
                                                 const float* __restrict__ c2w,
                                                 const float* __restrict__ c2b,
                                                 float* __restrict__ out) {
  __shared__ float hS[128];
  __shared__ float clsS[2];
  int b = blockIdx.x, t = threadIdx.x;
  float acc = c1b[t];
  for (int p = 0; p < 256; p++) acc += repA[b * 256 + p] * c1w[p * 128 + t];
  hS[t] = acc > 0.f ? acc : 0.01f * acc;
  __syncthreads();
  if (t < 2) {
    float a2 = c2b[t];
    for (int j = 0; j < 128; j++) a2 += hS[j] * c2w[j * 2 + t];
    clsS[t] = a2;
  }
  __syncthreads();
  if (t == 0) {
    float c0 = clsS[0], c1 = clsS[1];
    float m = fmaxf(c0, c1);
    float e0 = __expf(c0 - m), e1 = __expf(c1 - m);
    float inv = 1.0f / (e0 + e1);
    float p0 = e0 * inv, p1 = e1 * inv;
    out[b * 2 + 0] = p0;
    out[b * 2 + 1] = p1;
    out[B_ * 2 + b] = (p1 > p0) ? 1.0f : 0.0f;
  }
}

extern "C" void kernel_launch(void* const* d_in, const int* in_sizes, int n_in,
                              void* d_out, int out_size, void* d_ws, size_t ws_size,
                              hipStream_t stream) {
  const float* x   = (const float*)d_in[0];
  const int*   seq = (const int*)d_in[1];
  const float* pw  = (const float*)d_in[2];
  const float* pb  = (const float*)d_in[3];
  const float* cw  = (const float*)d_in[4];
  const float* cb  = (const float*)d_in[5];
  const float* aw  = (const float*)d_in[6];
  const float* ab  = (const float*)d_in[7];
  const float* c1w = (const float*)d_in[8];
  const float* c1b = (const float*)d_in[9];
  const float* c2w = (const float*)d_in[10];
  const float* c2b = (const float*)d_in[11];
  float* out = (float*)d_out;

  char* ws = (char*)d_ws;
  // proj16 (8 MiB) aliases E16 (16 MiB): proj16 dies (k_conv) before E16 written
  unsigned short* proj16 = (unsigned short*)(ws);
  unsigned short* E16    = (unsigned short*)(ws);                     // 16 MiB @ 0
  unsigned short* rep16  = (unsigned short*)(ws + (size_t)16777216);  // 8 MiB
  unsigned char*  repF8  = (unsigned char*)(ws + (size_t)25165824);   // 4 MiB
  unsigned char*  awB8   = (unsigned char*)(ws + (size_t)29360128);   // 1 MiB
  unsigned short* pwB    = (unsigned short*)(ws + (size_t)30408704);  // 512 KiB
  unsigned short* wtB    = (unsigned short*)(ws + (size_t)30932992);  // 384 KiB
  float*          Z      = (float*)(ws + (size_t)31326208);           // 64 KiB
  float*          wB     = (float*)(ws + (size_t)31391744);           // 64 KiB
  float*          repA   = (float*)(ws + (size_t)31457280);           // 32 KiB

  k_zero<<<160, 256, 0, stream>>>(Z);  // Z + wB + repA contiguous (40960 floats)
  k_pwB<<<dim3(8, 16), 256, 0, stream>>>(pw, pwB);
  k_wtB<<<dim3(8, 12), 256, 0, stream>>>(cw, wtB);
  k_awB8<<<dim3(256, 2), 256, 0, stream>>>(aw, awB8);

  k_proj_mfma<<<256, 256, 0, stream>>>(x, pwB, pb, proj16);
  k_conv_mfma<<<256, 256, 0, stream>>>(proj16, wtB, cb, seq, rep16);
  k_swz8<<<dim3(1024, 2), 256, 0, stream>>>(rep16, repF8);
  k_attn_mfma<<<dim3(256, 4), 256, 0, stream>>>(repF8, awB8, ab, E16, Z);
  k_w<<<dim3(32, 8), 512, 0, stream>>>(E16, Z, wB);
  k_final_a<<<dim3(32, 8), 256, 0, stream>>>(rep16, wB, repA);
  k_final_b<<<32, 128, 0, stream>>>(repA, c1w, c1b, c2w, c2b, out);
}

// Round 11
// 220.068 us; speedup vs baseline: 1.6810x; 1.0227x over previous
//
#include <hip/hip_runtime.h>
#include <hip/hip_fp8.h>

#define B_ 32
#define S_ 512
#define E_ 1024
#define P_ 256
#define HH 8
// rows = B*S = 16384

typedef __attribute__((ext_vector_type(8))) short bf16x8;
typedef __attribute__((ext_vector_type(8))) unsigned short us8;
typedef __attribute__((ext_vector_type(4))) unsigned short us4;
typedef __attribute__((ext_vector_type(16))) float f32x16;
typedef __attribute__((ext_vector_type(4))) float f32x4;
typedef __attribute__((ext_vector_type(8))) unsigned char u8x8;

#define SA 8.0f
#define SB 16.0f
#define SINV (1.0f / 128.0f)

static __device__ __forceinline__ unsigned short f2bf(float f) {
  union { float f; unsigned int u; } v;
  v.f = f;
  unsigned int r = (v.u + 0x7FFFu + ((v.u >> 16) & 1u)) >> 16;
  return (unsigned short)r;
}
static __device__ __forceinline__ float bf2f(unsigned short u) {
  union { unsigned int u; float f; } v;
  v.u = ((unsigned int)u) << 16;
  return v.f;
}
static __device__ __forceinline__ unsigned char f2fp8(float f) {
  return (unsigned char)__hip_cvt_float_to_fp8(f, __HIP_SATFINITE, __HIP_E4M3);
}

// ---------------- merged prep: zero + pwB + wtB + awB8, range-dispatched ---------
// blocks: [0,160) zero 40960 floats; [160,288) pwB; [288,384) wtB; [384,896) awB8
__global__ __launch_bounds__(256) void k_prep(const float* __restrict__ pw,
                                              const float* __restrict__ cw,
                                              const float* __restrict__ aw,
                                              unsigned short* __restrict__ pwB,
                                              unsigned short* __restrict__ wtB,
                                              unsigned char* __restrict__ awB8,
                                              float* __restrict__ zbase) {
  int bid = blockIdx.x;
  int t = threadIdx.x;
  if (bid < 160) {  // zero Z + wB + repA (contiguous)
    zbase[bid * 256 + t] = 0.f;
    return;
  }
  bid -= 160;
  if (bid < 128) {  // pw [k][n] -> pwB 32x32-frag bf16 (8 g x 16 kc-quads)
    int g = bid >> 4, kc = (bid & 15) * 4 + (t >> 6);
    int l = t & 63;
    int n = g * 32 + (l & 31);
    int kbase = kc * 16 + (l >> 5) * 8;
    us8 v;
#pragma unroll
    for (int j = 0; j < 8; j++) v[j] = f2bf(pw[(size_t)(kbase + j) * P_ + n]);
    *(us8*)(pwB + ((size_t)g * 64 + kc) * 512 + l * 8) = v;
    return;
  }
  bid -= 128;
  if (bid < 96) {  // conv_w (O,I,K) -> wtB 32x32-frag bf16 (8 g x 12 kidx-quads)
    int g = bid / 12, kidx = (bid % 12) * 4 + (t >> 6);
    int l = t & 63;
    int o = g * 32 + (l & 31);
    int xb = kidx * 16 + (l >> 5) * 8;
    us8 v;
#pragma unroll
    for (int j = 0; j < 8; j++) {
      int x = xb + j;
      int k = x >> 8, i = x & 255;
      v[j] = f2bf(cw[(size_t)o * 768 + i * 3 + k]);
    }
    *(us8*)(wtB + ((size_t)g * 48 + kidx) * 512 + l * 8) = v;
    return;
  }
  bid -= 96;
  {  // attn_w [k][j] -> awB8 16x16x32-frag fp8 x SB (256 g x 2 ks-quads)
    int g = bid >> 1, ks = (bid & 1) * 4 + (t >> 6);
    int l = t & 63;
    int j0 = g * 16 + (l & 15);
    int kbase = ks * 32 + (l >> 4) * 8;
    u8x8 v;
#pragma unroll
    for (int j = 0; j < 8; j++) v[j] = f2fp8(aw[(size_t)(kbase + j) * 4096 + j0] * SB);
    *(u8x8*)(awB8 + ((size_t)g * 8 + ks) * 512 + l * 8) = v;
  }
}

// ---------------- prep D: rep16 bf16 -> repF8 16x16x32-frag fp8 (xSA) ------------
__global__ __launch_bounds__(256) void k_swz8(const unsigned short* __restrict__ src,
                                              unsigned char* __restrict__ dst) {
  int g = blockIdx.x, ks = blockIdx.y * 4 + (threadIdx.x >> 6);
  int l = threadIdx.x & 63;
  us8 v = *(const us8*)(src + (size_t)(g * 16 + (l & 15)) * 256 + ks * 32 + (l >> 4) * 8);
  u8x8 o;
#pragma unroll
  for (int j = 0; j < 8; j++) o[j] = f2fp8(bf2f(v[j]) * SA);
  *(u8x8*)(dst + ((size_t)g * 8 + ks) * 512 + l * 8) = o;
}

// ---------------- stage 1: proj16 = bf16(x @ pw + pb)  (16384x1024x256) ----------
// 512 threads = 8 waves, each 64 rows x 32 cols (2 chains, 32 AGPR). Grid 256
// -> 8 waves/CU = 2 waves/SIMD (was 1 at 256 threads — zero latency hiding).
__global__ __launch_bounds__(512) void k_proj_mfma(const float* __restrict__ x,
                                                   const unsigned short* __restrict__ pwB,
                                                   const float* __restrict__ pb,
                                                   unsigned short* __restrict__ proj16) {
  __shared__ unsigned short As[16 * 64 * 8];  // (kk2*64 + row)*8, 16 KiB
  const int m0 = blockIdx.x * 64;
  const int t = threadIdx.x;
  const int w = t >> 6, lane = t & 63, ln31 = lane & 31, kh = lane >> 5;
  const int c0 = w * 32;

  f32x16 acc0, acc1;
#pragma unroll
  for (int r = 0; r < 16; r++) { acc0[r] = 0.f; acc1[r] = 0.f; }

  const unsigned short* bp = pwB + (size_t)w * 64 * 512 + lane * 8;

  for (int kc = 0; kc < E_; kc += 128) {
#pragma unroll
    for (int i = 0; i < 4; i++) {
      int c = t + i * 512;
      int row = c >> 5, pos = c & 31;
      float4 v = *(const float4*)(x + (size_t)(m0 + row) * E_ + kc + pos * 4);
      us4 h;
      h[0] = f2bf(v.x); h[1] = f2bf(v.y); h[2] = f2bf(v.z); h[3] = f2bf(v.w);
      *(us4*)&As[((pos >> 1) * 64 + row) * 8 + (pos & 1) * 4] = h;
    }
    __syncthreads();
    const int kcs = kc >> 4;
#pragma unroll
    for (int kk = 0; kk < 8; kk++) {
      bf16x8 a0 = *(const bf16x8*)&As[((2 * kk + kh) * 64 + ln31) * 8];
      bf16x8 a1 = *(const bf16x8*)&As[((2 * kk + kh) * 64 + 32 + ln31) * 8];
      bf16x8 b  = *(const bf16x8*)(bp + (size_t)(kcs + kk) * 512);
      acc0 = __builtin_amdgcn_mfma_f32_32x32x16_bf16(a0, b, acc0, 0, 0, 0);
      acc1 = __builtin_amdgcn_mfma_f32_32x32x16_bf16(a1, b, acc1, 0, 0, 0);
    }
    __syncthreads();
  }
  float pbv = pb[c0 + ln31];
#pragma unroll
  for (int r = 0; r < 16; r++) {
    int rl = (r & 3) + 8 * (r >> 2) + 4 * kh;
    proj16[(size_t)(m0 + rl) * P_ + c0 + ln31]      = f2bf(acc0[r] + pbv);
    proj16[(size_t)(m0 + 32 + rl) * P_ + c0 + ln31] = f2bf(acc1[r] + pbv);
  }
}

// ---------------- stage 2: conv-as-3-shift-GEMM -> rep16 (16384x768x256) ---------
// 512 threads = 8 waves, each 64 rows x 32 cols. Grid 256 -> 2 waves/SIMD.
__global__ __launch_bounds__(512) void k_conv_mfma(const unsigned short* __restrict__ proj16,
                                                   const unsigned short* __restrict__ wtB,
                                                   const float* __restrict__ cb,
                                                   const int* __restrict__ seq,
                                                   unsigned short* __restrict__ rep16) {
  __shared__ unsigned short As[32 * 66 * 8];  // (kk2*66 + row)*8, 33 KiB
  const int m0 = blockIdx.x * 64;
  const int bb = m0 >> 9, s0 = m0 & 511;
  const int t = threadIdx.x;
  const int w = t >> 6, lane = t & 63, ln31 = lane & 31, kh = lane >> 5;
  const int c0 = w * 32;

#pragma unroll
  for (int i = 0; i < 5; i++) {
    int c = t + i * 512;
    if (c < 2112) {
      int row = c >> 5, kk2 = c & 31;
      us8 v = {0, 0, 0, 0, 0, 0, 0, 0};
      if (s0 + row <= 511)
        v = *(const us8*)(proj16 + (size_t)(bb * S_ + s0 + row) * P_ + kk2 * 8);
      *(us8*)&As[(kk2 * 66 + row) * 8] = v;
    }
  }
  __syncthreads();

  f32x16 acc0, acc1;
#pragma unroll
  for (int r = 0; r < 16; r++) { acc0[r] = 0.f; acc1[r] = 0.f; }

  const unsigned short* bbase = wtB + (size_t)w * 48 * 512 + lane * 8;

#pragma unroll
  for (int k = 0; k < 3; k++) {
#pragma unroll
    for (int kk = 0; kk < 16; kk++) {
      bf16x8 a0 = *(const bf16x8*)&As[((2 * kk + kh) * 66 + k + ln31) * 8];
      bf16x8 a1 = *(const bf16x8*)&As[((2 * kk + kh) * 66 + k + 32 + ln31) * 8];
      bf16x8 b  = *(const bf16x8*)(bbase + (size_t)(k * 16 + kk) * 512);
      acc0 = __builtin_amdgcn_mfma_f32_32x32x16_bf16(a0, b, acc0, 0, 0, 0);
      acc1 = __builtin_amdgcn_mfma_f32_32x32x16_bf16(a1, b, acc1, 0, 0, 0);
    }
  }

  int l = seq[bb];
  float cbv = cb[c0 + ln31];
#pragma unroll
  for (int r = 0; r < 16; r++) {
    int rl = (r & 3) + 8 * (r >> 2) + 4 * kh;
    int s_a = s0 + rl, s_b = s0 + 32 + rl;
    float ma = (s_a >= 1 && s_a <= 509 && s_a < l - 1) ? 1.f : 0.f;
    float mb = (s_b >= 1 && s_b <= 509 && s_b < l - 1) ? 1.f : 0.f;
    rep16[(size_t)(m0 + rl) * P_ + c0 + ln31]      = f2bf(fmaxf(acc0[r] + cbv, 0.f) * ma);
    rep16[(size_t)(m0 + 32 + rl) * P_ + c0 + ln31] = f2bf(fmaxf(acc1[r] + cbv, 0.f) * mb);
  }
}

// ---------------- stage 3: fp8 16x16x32 MFMA logits + exp + h-fold + Z -> E16 ----
// (unchanged R10 — best known: 8 indep chains, A fp8 register-resident, no LDS)
__global__ __launch_bounds__(256, 2) void k_attn_mfma(const unsigned char* __restrict__ repF8,
                                                      const unsigned char* __restrict__ awB8,
                                                      const float* __restrict__ ab,
                                                      unsigned short* __restrict__ E16,
                                                      float* __restrict__ Z) {
  const int m0 = blockIdx.x * 64;
  const int q0 = blockIdx.y * 128;
  const int t = threadIdx.x;
  const int w = t >> 6, lane = t & 63;
  const int ln15 = lane & 15, l4 = lane >> 4;

  long ar[4][8];
  {
    const unsigned char* abase = repF8 + (size_t)(m0 >> 4) * 8 * 512 + lane * 8;
#pragma unroll
    for (int rt = 0; rt < 4; rt++)
#pragma unroll
      for (int ks = 0; ks < 8; ks++)
        ar[rt][ks] = *(const long*)(abase + (size_t)(rt * 8 + ks) * 512);
  }

  const int qg = (q0 >> 5) + w;  // q-group 0..15 (32 q each)

  f32x4 ef[8];
#pragma unroll
  for (int i = 0; i < 8; i++) ef[i] = (f32x4){0.f, 0.f, 0.f, 0.f};

#pragma unroll 1
  for (int h = 0; h < HH; h++) {
    const unsigned char* bh = awB8 + (size_t)(h * 32 + qg * 2) * 8 * 512 + lane * 8;
    f32x4 acc[8];
#pragma unroll
    for (int i = 0; i < 8; i++) acc[i] = (f32x4){0.f, 0.f, 0.f, 0.f};
#pragma unroll
    for (int ks = 0; ks < 8; ks++) {
      long b0 = *(const long*)(bh + (size_t)ks * 512);
      long b1 = *(const long*)(bh + (size_t)(8 + ks) * 512);
#pragma unroll
      for (int rt = 0; rt < 4; rt++) {
        acc[rt * 2 + 0] = __builtin_amdgcn_mfma_f32_16x16x32_fp8_fp8(ar[rt][ks], b0, acc[rt * 2 + 0], 0, 0, 0);
        acc[rt * 2 + 1] = __builtin_amdgcn_mfma_f32_16x16x32_fp8_fp8(ar[rt][ks], b1, acc[rt * 2 + 1], 0, 0, 0);
      }
    }
    float bias0 = ab[h * 512 + qg * 32 + ln15];
    float bias1 = ab[h * 512 + qg * 32 + 16 + ln15];
#pragma unroll
    for (int rt = 0; rt < 4; rt++)
#pragma unroll
      for (int r = 0; r < 4; r++) {
        ef[rt * 2 + 0][r] += __expf(acc[rt * 2 + 0][r] * SINV + bias0);
        ef[rt * 2 + 1][r] += __expf(acc[rt * 2 + 1][r] * SINV + bias1);
      }
  }

#pragma unroll
  for (int rt = 0; rt < 4; rt++)
#pragma unroll
    for (int r = 0; r < 4; r++) {
      int row = m0 + rt * 16 + l4 * 4 + r;
      E16[(size_t)row * 512 + qg * 32 + ln15]      = f2bf(ef[rt * 2 + 0][r]);
      E16[(size_t)row * 512 + qg * 32 + 16 + ln15] = f2bf(ef[rt * 2 + 1][r]);
    }

#pragma unroll
  for (int rt = 0; rt < 4; rt++)
#pragma unroll
    for (int r = 0; r < 4; r++) {
      float z = ef[rt * 2 + 0][r] + ef[rt * 2 + 1][r];
#pragma unroll
      for (int st = 8; st >= 1; st >>= 1) z += __shfl_xor(z, st, 64);
      if (ln15 == 0) atomicAdd(&Z[m0 + rt * 16 + l4 * 4 + r], z);
    }
}

// ---------------- stage 4: w[b,q] = (1/H) sum_s E16[b,s,q]/Z[b,s] ----------------
__global__ __launch_bounds__(512) void k_w(const unsigned short* __restrict__ E16,
                                           const float* __restrict__ Z,
                                           float* __restrict__ wB) {
  __shared__ float rZ[64];
  int b = blockIdx.x, c = blockIdx.y, t = threadIdx.x;
  int s0 = c * 64;
  if (t < 64) rZ[t] = 1.0f / Z[b * 512 + s0 + t];
  __syncthreads();
  float acc = 0.f;
#pragma unroll 8
  for (int s = 0; s < 64; s++)
    acc += bf2f(E16[(size_t)(b * 512 + s0 + s) * 512 + t]) * rZ[s];
  atomicAdd(&wB[b * 512 + t], acc * (1.0f / HH));
}

// ---------------- stage 5a: repA[b,p] = sum_q w[b,q] * rep16[b,q,p] --------------
__global__ __launch_bounds__(256) void k_final_a(const unsigned short* __restrict__ rep16,
                                                 const float* __restrict__ wB,
                                                 float* __restrict__ repA) {
  __shared__ float wS[64];
  int b = blockIdx.x, qc = blockIdx.y, t = threadIdx.x;
  if (t < 64) wS[t] = wB[b * 512 + qc * 64 + t];
  __syncthreads();
  int p0 = (t & 63) * 4, qo = t >> 6;
  float a0 = 0.f, a1 = 0.f, a2 = 0.f, a3 = 0.f;
  for (int q = qo; q < 64; q += 4) {
    us4 v = *(const us4*)(rep16 + (size_t)(b * 512 + qc * 64 + q) * 256 + p0);
    float wq = wS[q];
    a0 += wq * bf2f(v[0]); a1 += wq * bf2f(v[1]);
    a2 += wq * bf2f(v[2]); a3 += wq * bf2f(v[3]);
  }
  atomicAdd(&repA[b * 256 + p0 + 0], a0);
  atomicAdd(&repA[b * 256 + p0 + 1], a1);
  atomicAdd(&repA[b * 256 + p0 + 2], a2);
  atomicAdd(&repA[b * 256 + p0 + 3], a3);
}

// ---------------- stage 5b: heads -> probs + argmax ------------------------------
__global__ __launch_bounds__(128) void k_final_b(const float* __restrict__ repA,
                                                 const float* __restrict__ c1w,
                                                 const float* __restrict__ c1b,
                                                 const float* __restrict__ c2w,
                                                 const float* __restrict__ c2b,
                                                 float* __restrict__ out) {
  __shared__ float hS[128];
  __shared__ float clsS[2];
  int b = blockIdx.x, t = threadIdx.x;
  float acc = c1b[t];
  for (int p = 0; p < 256; p++) acc += repA[b * 256 + p] * c1w[p * 128 + t];
  hS[t] = acc > 0.f ? acc : 0.01f * acc;
  __syncthreads();
  if (t < 2) {
    float a2 = c2b[t];
    for (int j = 0; j < 128; j++) a2 += hS[j] * c2w[j * 2 + t];
    clsS[t] = a2;
  }
  __syncthreads();
  if (t == 0) {
    float c0 = clsS[0], c1 = clsS[1];
    float m = fmaxf(c0, c1);
    float e0 = __expf(c0 - m), e1 = __expf(c1 - m);
    float inv = 1.0f / (e0 + e1);
    float p0 = e0 * inv, p1 = e1 * inv;
    out[b * 2 + 0] = p0;
    out[b * 2 + 1] = p1;
    out[B_ * 2 + b] = (p1 > p0) ? 1.0f : 0.0f;
  }
}

extern "C" void kernel_launch(void* const* d_in, const int* in_sizes, int n_in,
                              void* d_out, int out_size, void* d_ws, size_t ws_size,
                              hipStream_t stream) {
  const float* x   = (const float*)d_in[0];
  const int*   seq = (const int*)d_in[1];
  const float* pw  = (const float*)d_in[2];
  const float* pb  = (const float*)d_in[3];
  const float* cw  = (const float*)d_in[4];
  const float* cb  = (const float*)d_in[5];
  const float* aw  = (const float*)d_in[6];
  const float* ab  = (const float*)d_in[7];
  const float* c1w = (const float*)d_in[8];
  const float* c1b = (const float*)d_in[9];
  const float* c2w = (const float*)d_in[10];
  const float* c2b = (const float*)d_in[11];
  float* out = (float*)d_out;

  char* ws = (char*)d_ws;
  // proj16 (8 MiB) aliases E16 (16 MiB): proj16 dies (k_conv) before E16 written
  unsigned short* proj16 = (unsigned short*)(ws);
  unsigned short* E16    = (unsigned short*)(ws);                     // 16 MiB @ 0
  unsigned short* rep16  = (unsigned short*)(ws + (size_t)16777216);  // 8 MiB
  unsigned char*  repF8  = (unsigned char*)(ws + (size_t)25165824);   // 4 MiB
  unsigned char*  awB8   = (unsigned char*)(ws + (size_t)29360128);   // 1 MiB
  unsigned short* pwB    = (unsigned short*)(ws + (size_t)30408704);  // 512 KiB
  unsigned short* wtB    = (unsigned short*)(ws + (size_t)30932992);  // 384 KiB
  float*          Z      = (float*)(ws + (size_t)31326208);           // 64 KiB
  float*          wB     = (float*)(ws + (size_t)31391744);           // 64 KiB
  float*          repA   = (float*)(ws + (size_t)31457280);           // 32 KiB

  k_prep<<<896, 256, 0, stream>>>(pw, cw, aw, pwB, wtB, awB8, Z);
  k_proj_mfma<<<256, 512, 0, stream>>>(x, pwB, pb, proj16);
  k_conv_mfma<<<256, 512, 0, stream>>>(proj16, wtB, cb, seq, rep16);
  k_swz8<<<dim3(1024, 2), 256, 0, stream>>>(rep16, repF8);
  k_attn_mfma<<<dim3(256, 4), 256, 0, stream>>>(repF8, awB8, ab, E16, Z);
  k_w<<<dim3(32, 8), 512, 0, stream>>>(E16, Z, wB);
  k_final_a<<<dim3(32, 8), 256, 0, stream>>>(rep16, wB, repA);
  k_final_b<<<32, 128, 0, stream>>>(repA, c1w, c1b, c2w, c2b, out);
}